// Round 2
// baseline (362.696 us; speedup 1.0000x reference)
//
#include <hip/hip_runtime.h>
#include <hip/hip_bf16.h>

#define NB 8
#define NS 1024
#define ND 768
#define NH 12
#define NC 64
#define NEG 0.2f
#define NCH 32   // chunks per (b,h) for vector prefix sums (chunk = 32 k's)

typedef __attribute__((ext_vector_type(8))) short bf16x8;
typedef __attribute__((ext_vector_type(4))) float f32x4;

static __device__ __forceinline__ float bf2f(unsigned short u) {
    union { float f; unsigned int i; } v; v.i = ((unsigned int)u) << 16; return v.f;
}
static __device__ __forceinline__ unsigned short f2bf(float f) {
    union { float f; unsigned int i; } v; v.f = f;
    unsigned int r = v.i + 0x7FFFu + ((v.i >> 16) & 1u);
    return (unsigned short)(r >> 16);
}

// ---------------- fp32 -> bf16 elementwise convert ----------------
__global__ void k_f32_to_bf16(const float* __restrict__ src, unsigned short* __restrict__ dst, int n) {
    int i = (blockIdx.x * blockDim.x + threadIdx.x) * 4;
    if (i >= n) return;
    float4 v = *reinterpret_cast<const float4*>(src + i);
    ushort4 o;
    o.x = f2bf(v.x); o.y = f2bf(v.y); o.z = f2bf(v.z); o.w = f2bf(v.w);
    *reinterpret_cast<ushort4*>(dst + i) = o;
}

// ---------------- fp32 [K,N] -> bf16 [N,K] transpose-convert ----------------
__global__ void k_transpose_conv(const float* __restrict__ src, unsigned short* __restrict__ dst,
                                 int K, int N) {
    __shared__ float tile[32][33];
    int k0 = blockIdx.y * 32, n0 = blockIdx.x * 32;
    int t = threadIdx.x;           // 256 threads
    int r = t >> 3, c4 = (t & 7) * 4;
    float4 v = *reinterpret_cast<const float4*>(src + (size_t)(k0 + r) * N + n0 + c4);
    tile[r][c4] = v.x; tile[r][c4 + 1] = v.y; tile[r][c4 + 2] = v.z; tile[r][c4 + 3] = v.w;
    __syncthreads();
    ushort4 o;
    o.x = f2bf(tile[c4][r]); o.y = f2bf(tile[c4 + 1][r]);
    o.z = f2bf(tile[c4 + 2][r]); o.w = f2bf(tile[c4 + 3][r]);
    *reinterpret_cast<ushort4*>(dst + (size_t)(n0 + r) * K + k0 + c4) = o;
}

// ---------------- combined bias: bias_tot[c] = b_fus[c] + sum_k bp[k]*Wf[768+k][c] ----------------
__global__ void k_bias_tot(const float* __restrict__ Wf, const float* __restrict__ bp,
                           const float* __restrict__ bfu, float* __restrict__ bias_tot) {
    int c = blockIdx.x * 256 + threadIdx.x;
    if (c >= ND) return;
    float acc = bfu[c];
#pragma unroll 8
    for (int k = 0; k < ND; k++) acc += bp[k] * Wf[(size_t)(ND + k) * ND + c];
    bias_tot[c] = acc;
}

// ---------------- a_src / a_dst: [B,H,S] dot of x with att vectors ----------------
__global__ void k_attn_vec(const unsigned short* __restrict__ x, const float* __restrict__ att_src,
                           const float* __restrict__ att_dst, float* __restrict__ a_src,
                           float* __restrict__ a_dst) {
    int bs = blockIdx.x;           // 0..B*S-1
    int c = threadIdx.x;           // 0..63
    int b = bs >> 10, s = bs & 1023;
    const unsigned short* xr = x + (size_t)bs * ND;
    float ps[NH], pd[NH];
#pragma unroll
    for (int h = 0; h < NH; h++) {
        float xv = bf2f(xr[h * 64 + c]);
        ps[h] = xv * att_src[h * 64 + c];
        pd[h] = xv * att_dst[h * 64 + c];
    }
#pragma unroll
    for (int off = 32; off >= 1; off >>= 1) {
#pragma unroll
        for (int h = 0; h < NH; h++) {
            ps[h] += __shfl_down(ps[h], off, 64);
            pd[h] += __shfl_down(pd[h], off, 64);
        }
    }
    if (c == 0) {
#pragma unroll
        for (int h = 0; h < NH; h++) {
            a_src[((size_t)b * NH + h) * NS + s] = ps[h];
            a_dst[((size_t)b * NH + h) * NS + s] = pd[h];
        }
    }
}

// ---------------- sort a_src per (b,h); emit su (sorted, max-subtracted), perm, e^u, e^{.2u},
//                  and their inclusive scalar prefix sums ----------------
__global__ __launch_bounds__(256) void k_sort(const float* __restrict__ a_src,
                                              float* __restrict__ su_g, int* __restrict__ perm_g,
                                              float* __restrict__ es1_g, float* __restrict__ es2_g,
                                              float* __restrict__ z1_g, float* __restrict__ z2_g,
                                              float* __restrict__ smax_g) {
    int bh = blockIdx.x, t = threadIdx.x;
    __shared__ float v[1024];
    __shared__ int ix[1024];
    __shared__ float e1[1024], e2[1024];
    __shared__ float w1[256], w2[256];
    for (int i = t; i < 1024; i += 256) { v[i] = a_src[(size_t)bh * 1024 + i]; ix[i] = i; }
    __syncthreads();
    for (int size = 2; size <= 1024; size <<= 1) {
        for (int stride = size >> 1; stride > 0; stride >>= 1) {
            for (int i = t; i < 1024; i += 256) {
                int j = i ^ stride;
                if (j > i) {
                    bool up = ((i & size) == 0);
                    float a = v[i], b = v[j];
                    if ((a > b) == up) {
                        v[i] = b; v[j] = a;
                        int tmp = ix[i]; ix[i] = ix[j]; ix[j] = tmp;
                    }
                }
            }
            __syncthreads();
        }
    }
    float sm = v[1023];
    __syncthreads();
    for (int i = t; i < 1024; i += 256) {
        float u = v[i] - sm;
        float a1 = __expf(u), a2 = __expf(0.2f * u);
        e1[i] = a1; e2[i] = a2;
        su_g[(size_t)bh * 1024 + i] = u;
        perm_g[(size_t)bh * 1024 + i] = ix[i];
        es1_g[(size_t)bh * 1024 + i] = a1;
        es2_g[(size_t)bh * 1024 + i] = a2;
    }
    if (t == 0) smax_g[bh] = sm;
    __syncthreads();
    // inclusive prefix scan of e1,e2 (1024) -> z1,z2
    int base = t * 4;
    float p0 = e1[base], p1v = p0 + e1[base + 1], p2v = p1v + e1[base + 2], p3v = p2v + e1[base + 3];
    float q0 = e2[base], q1v = q0 + e2[base + 1], q2v = q1v + e2[base + 2], q3v = q2v + e2[base + 3];
    w1[t] = p3v; w2[t] = q3v;
    __syncthreads();
    for (int off = 1; off < 256; off <<= 1) {
        float x1 = (t >= off) ? w1[t - off] : 0.f;
        float x2 = (t >= off) ? w2[t - off] : 0.f;
        __syncthreads();
        w1[t] += x1; w2[t] += x2;
        __syncthreads();
    }
    float o1 = w1[t] - p3v, o2 = w2[t] - q3v;
    z1_g[(size_t)bh * 1024 + base + 0] = o1 + p0;
    z1_g[(size_t)bh * 1024 + base + 1] = o1 + p1v;
    z1_g[(size_t)bh * 1024 + base + 2] = o1 + p2v;
    z1_g[(size_t)bh * 1024 + base + 3] = o1 + p3v;
    z2_g[(size_t)bh * 1024 + base + 0] = o2 + q0;
    z2_g[(size_t)bh * 1024 + base + 1] = o2 + q1v;
    z2_g[(size_t)bh * 1024 + base + 2] = o2 + q2v;
    z2_g[(size_t)bh * 1024 + base + 3] = o2 + q3v;
}

// ---------------- per-chunk vector sums: Csum[bh][cc][{1,2}][c] ----------------
__global__ void k_scanA(const unsigned short* __restrict__ x_bf, const int* __restrict__ perm_g,
                        const float* __restrict__ es1_g, const float* __restrict__ es2_g,
                        float* __restrict__ Csum) {
    int cc = blockIdx.x, bh = blockIdx.y, c = threadIdx.x;   // 64 threads
    int b = bh / NH, h = bh % NH;
    const unsigned short* xb = x_bf + (size_t)b * NS * ND + h * 64 + c;
    float s1 = 0.f, s2 = 0.f;
    int kb = bh * 1024 + cc * 32;
#pragma unroll 4
    for (int kk = 0; kk < 32; kk++) {
        int j = perm_g[kb + kk];
        float xv = bf2f(xb[(size_t)j * ND]);
        s1 += es1_g[kb + kk] * xv;
        s2 += es2_g[kb + kk] * xv;
    }
    size_t o = ((size_t)(bh * NCH + cc) * 2) * 64 + c;
    Csum[o] = s1;
    Csum[o + 64] = s2;
}

// ---------------- in-place inclusive scan of chunk sums over cc ----------------
__global__ void k_chpref(float* __restrict__ Csum) {
    int bh = blockIdx.x, c = threadIdx.x;   // 64 threads
    float a1 = 0.f, a2 = 0.f;
    for (int cc = 0; cc < NCH; cc++) {
        size_t o = ((size_t)(bh * NCH + cc) * 2) * 64 + c;
        a1 += Csum[o];     Csum[o] = a1;
        a2 += Csum[o + 64]; Csum[o + 64] = a2;
    }
}

// ---------------- apply: per row binary-search threshold, combine prefix pieces ----------------
__global__ __launch_bounds__(256) void k_apply(const unsigned short* __restrict__ x_bf,
                                               const float* __restrict__ su_g,
                                               const int* __restrict__ perm_g,
                                               const float* __restrict__ es1_g,
                                               const float* __restrict__ es2_g,
                                               const float* __restrict__ z1_g,
                                               const float* __restrict__ z2_g,
                                               const float* __restrict__ CP,
                                               const float* __restrict__ a_dst,
                                               const float* __restrict__ smax_g,
                                               const float* __restrict__ b_gat,
                                               unsigned short* __restrict__ gat) {
    __shared__ float su[1024], z1[1024], z2[1024], e1[1024], e2[1024];
    __shared__ int pm[1024];
    int bh = blockIdx.y, t = threadIdx.x;
    size_t gb = (size_t)bh * 1024;
    for (int i = t; i < 1024; i += 256) {
        su[i] = su_g[gb + i]; z1[i] = z1_g[gb + i]; z2[i] = z2_g[gb + i];
        e1[i] = es1_g[gb + i]; e2[i] = es2_g[gb + i]; pm[i] = perm_g[gb + i];
    }
    __syncthreads();
    int wave = t >> 6, lane = t & 63;
    int b = bh / NH, h = bh % NH;
    float t1v = CP[((size_t)(bh * NCH + NCH - 1) * 2) * 64 + lane];
    float z1tot = z1[1023];
    float sm = smax_g[bh];
    const unsigned short* xb = x_bf + (size_t)b * NS * ND + h * 64 + lane;
    float bias = b_gat[h * 64 + lane];
#pragma unroll
    for (int q = 0; q < 4; q++) {
        int i = blockIdx.x * 16 + wave * 4 + q;
        float d = a_dst[gb + i];
        float dm = d + sm;
        float m = dm > 0.f ? dm : NEG * dm;
        float c1 = __expf(dm - m);
        float c2 = __expf(NEG * dm - m);
        float vthr = -d - sm;
        int lo = 0, hi = 1024;
#pragma unroll
        for (int it = 0; it < 10; it++) {
            int mid = (lo + hi) >> 1;
            if (su[mid] <= vthr) lo = mid + 1; else hi = mid;
        }
        int tt = lo;
        float p1 = 0.f, p2 = 0.f, zz1 = 0.f, zz2 = 0.f;
        if (tt > 0) { zz1 = z1[tt - 1]; zz2 = z2[tt - 1]; }
        int cct = tt >> 5;
        if (cct > 0) {
            size_t ci = ((size_t)(bh * NCH + cct - 1) * 2) * 64 + lane;
            p1 = CP[ci]; p2 = CP[ci + 64];
        }
        for (int k = cct * 32; k < tt; k++) {
            float xv = bf2f(xb[(size_t)pm[k] * ND]);
            p1 += e1[k] * xv;
            p2 += e2[k] * xv;
        }
        float num = c1 * (t1v - p1) + c2 * p2;
        float Z = c1 * (z1tot - zz1) + c2 * zz2;
        float o = num / Z + bias;
        gat[((size_t)(b * NS + i)) * ND + h * 64 + lane] = f2bf(o);
    }
}

// ---------------- GEMM: C[M,N] = A[M,K] @ Bt[N,K]^T (+bias) (+acc) ----------------
template <bool OUT_BF16, bool ACC, bool BIAS>
__global__ __launch_bounds__(256) void k_gemm(const unsigned short* __restrict__ A,
                                              const unsigned short* __restrict__ Bt,
                                              const float* __restrict__ bias,
                                              void* __restrict__ Cout,
                                              int M, int N, int K, int lda, int ldb) {
    __shared__ alignas(16) unsigned short sA[128][40];
    __shared__ alignas(16) unsigned short sB[128][40];
    int m0 = blockIdx.y * 128, n0 = blockIdx.x * 128;
    int t = threadIdx.x;
    int wave = t >> 6, lane = t & 63;
    int wm = wave >> 1, wn = wave & 1;
    int lr = lane & 15, kg = (lane >> 4) * 8;
    f32x4 acc[4][4] = {};
    for (int k0 = 0; k0 < K; k0 += 32) {
        __syncthreads();
#pragma unroll
        for (int u = 0; u < 2; u++) {
            int idx = t + u * 256;
            int r = idx >> 2, sg = (idx & 3) * 8;
            *reinterpret_cast<bf16x8*>(&sA[r][sg]) =
                *reinterpret_cast<const bf16x8*>(A + (size_t)(m0 + r) * lda + k0 + sg);
            *reinterpret_cast<bf16x8*>(&sB[r][sg]) =
                *reinterpret_cast<const bf16x8*>(Bt + (size_t)(n0 + r) * ldb + k0 + sg);
        }
        __syncthreads();
        bf16x8 af[4], bfr[4];
#pragma unroll
        for (int m = 0; m < 4; m++) af[m] = *reinterpret_cast<bf16x8*>(&sA[wm * 64 + m * 16 + lr][kg]);
#pragma unroll
        for (int n = 0; n < 4; n++) bfr[n] = *reinterpret_cast<bf16x8*>(&sB[wn * 64 + n * 16 + lr][kg]);
#pragma unroll
        for (int m = 0; m < 4; m++)
#pragma unroll
            for (int n = 0; n < 4; n++)
                acc[m][n] = __builtin_amdgcn_mfma_f32_16x16x32_bf16(af[m], bfr[n], acc[m][n], 0, 0, 0);
    }
    int rg = (lane >> 4) * 4;
#pragma unroll
    for (int m = 0; m < 4; m++) {
#pragma unroll
        for (int n = 0; n < 4; n++) {
            int col = n0 + wn * 64 + n * 16 + lr;
            float bv = BIAS ? bias[col] : 0.0f;
#pragma unroll
            for (int r = 0; r < 4; r++) {
                int row = m0 + wm * 64 + m * 16 + rg + r;
                float v = acc[m][n][r] + bv;
                if (OUT_BF16) {
                    ((unsigned short*)Cout)[(size_t)row * N + col] = f2bf(v);
                } else {
                    float* o = (float*)Cout + (size_t)row * N + col;
                    if (ACC) v += *o;
                    *o = v;
                }
            }
        }
    }
}

extern "C" void kernel_launch(void* const* d_in, const int* in_sizes, int n_in,
                              void* d_out, int out_size, void* d_ws, size_t ws_size,
                              hipStream_t stream) {
    const float* hs  = (const float*)d_in[0];
    const float* to  = (const float*)d_in[1];
    const float* Wg  = (const float*)d_in[2];
    const float* asv = (const float*)d_in[3];
    const float* adv = (const float*)d_in[4];
    const float* bg  = (const float*)d_in[5];
    const float* Wp  = (const float*)d_in[6];
    const float* bp  = (const float*)d_in[7];
    const float* Wf  = (const float*)d_in[8];
    const float* bfu = (const float*)d_in[9];
    float* out = (float*)d_out;

    char* ws = (char*)d_ws;
    size_t off = 0;
    auto alloc = [&](size_t bytes) -> void* {
        void* p = ws + off;
        off = (off + bytes + 255) & ~(size_t)255;
        return p;
    };
    const size_t NBSD = (size_t)NB * NS * ND;
    const int NBH = NB * NH;
    unsigned short* h_bf   = (unsigned short*)alloc(NBSD * 2);  // later reused as gat_bf
    unsigned short* x_bf   = (unsigned short*)alloc(NBSD * 2);
    unsigned short* t_bf   = (unsigned short*)alloc(NBSD * 2);
    unsigned short* WgT    = (unsigned short*)alloc((size_t)ND * ND * 2);
    unsigned short* Wp_bf  = (unsigned short*)alloc((size_t)ND * ND * 2);
    unsigned short* WfT    = (unsigned short*)alloc((size_t)2 * ND * ND * 2);
    unsigned short* WcombT = (unsigned short*)alloc((size_t)ND * ND * 2);
    float* bias_tot = (float*)alloc((size_t)ND * 4);
    float* a_src = (float*)alloc((size_t)NBH * NS * 4);
    float* a_dst = (float*)alloc((size_t)NBH * NS * 4);
    float* su_g  = (float*)alloc((size_t)NBH * NS * 4);
    int*   perm  = (int*)alloc((size_t)NBH * NS * 4);
    float* es1   = (float*)alloc((size_t)NBH * NS * 4);
    float* es2   = (float*)alloc((size_t)NBH * NS * 4);
    float* z1    = (float*)alloc((size_t)NBH * NS * 4);
    float* z2    = (float*)alloc((size_t)NBH * NS * 4);
    float* smaxb = (float*)alloc((size_t)NBH * 4);
    float* Csum  = (float*)alloc((size_t)NBH * NCH * 2 * 64 * 4);

    int n = (int)NBSD;
    k_f32_to_bf16<<<n / 4 / 256, 256, 0, stream>>>(hs, h_bf, n);
    k_f32_to_bf16<<<n / 4 / 256, 256, 0, stream>>>(to, t_bf, n);
    k_f32_to_bf16<<<(ND * ND) / 4 / 256, 256, 0, stream>>>(Wp, Wp_bf, ND * ND);
    k_transpose_conv<<<dim3(ND / 32, ND / 32), 256, 0, stream>>>(Wg, WgT, ND, ND);
    k_transpose_conv<<<dim3(ND / 32, 2 * ND / 32), 256, 0, stream>>>(Wf, WfT, 2 * ND, ND);

    // WcombT[n][k] = sum_r WfT[n][768+r] * Wp[k][r]   (Wcomb = Wp @ Wf_bot)
    k_gemm<true, false, false><<<dim3(ND / 128, ND / 128), 256, 0, stream>>>(
        WfT + ND, Wp_bf, nullptr, WcombT, ND, ND, ND, 2 * ND, ND);
    k_bias_tot<<<3, 256, 0, stream>>>(Wf, bp, bfu, bias_tot);

    // GEMM1: x = hs @ W_gat  -> bf16
    k_gemm<true, false, false><<<dim3(ND / 128, NB * NS / 128), 256, 0, stream>>>(
        h_bf, WgT, nullptr, x_bf, NB * NS, ND, ND, ND, ND);

    k_attn_vec<<<NB * NS, 64, 0, stream>>>(x_bf, asv, adv, a_src, a_dst);
    k_sort<<<NBH, 256, 0, stream>>>(a_src, su_g, perm, es1, es2, z1, z2, smaxb);
    k_scanA<<<dim3(NCH, NBH), 64, 0, stream>>>(x_bf, perm, es1, es2, Csum);
    k_chpref<<<NBH, 64, 0, stream>>>(Csum);

    // apply -> gat_bf (reuse h_bf region), adds b_gat
    unsigned short* gat_bf = h_bf;
    k_apply<<<dim3(NS / 16, NBH), 256, 0, stream>>>(x_bf, su_g, perm, es1, es2, z1, z2,
                                                    Csum, a_dst, smaxb, bg, gat_bf);

    // out = t @ Wf_top + bias_tot ; out += gat @ Wcomb
    k_gemm<false, false, true><<<dim3(ND / 128, NB * NS / 128), 256, 0, stream>>>(
        t_bf, WfT, bias_tot, out, NB * NS, ND, ND, ND, 2 * ND);
    k_gemm<false, true, false><<<dim3(ND / 128, NB * NS / 128), 256, 0, stream>>>(
        gat_bf, WcombT, nullptr, out, NB * NS, ND, ND, ND, ND);
}

// Round 3
// 256.565 us; speedup vs baseline: 1.4137x; 1.4137x over previous
//
#include <hip/hip_runtime.h>
#include <hip/hip_bf16.h>

#define NB 8
#define NS 1024
#define ND 768
#define NH 12
#define NC 64
#define NEG 0.2f
#define NBUK 256

typedef __attribute__((ext_vector_type(8))) short bf16x8;
typedef __attribute__((ext_vector_type(4))) float f32x4;

static __device__ __forceinline__ float bf2f(unsigned short u) {
    union { float f; unsigned int i; } v; v.i = ((unsigned int)u) << 16; return v.f;
}
static __device__ __forceinline__ unsigned short f2bf(float f) {
    union { float f; unsigned int i; } v; v.f = f;
    unsigned int r = v.i + 0x7FFFu + ((v.i >> 16) & 1u);
    return (unsigned short)(r >> 16);
}

// ---------------- fp32 -> bf16 elementwise convert ----------------
__global__ void k_f32_to_bf16(const float* __restrict__ src, unsigned short* __restrict__ dst, int n) {
    int i = (blockIdx.x * blockDim.x + threadIdx.x) * 4;
    if (i >= n) return;
    float4 v = *reinterpret_cast<const float4*>(src + i);
    ushort4 o;
    o.x = f2bf(v.x); o.y = f2bf(v.y); o.z = f2bf(v.z); o.w = f2bf(v.w);
    *reinterpret_cast<ushort4*>(dst + i) = o;
}

// ---------------- fp32 [K,N] -> bf16 [N,K] transpose-convert ----------------
__global__ void k_transpose_conv(const float* __restrict__ src, unsigned short* __restrict__ dst,
                                 int K, int N) {
    __shared__ float tile[32][33];
    int k0 = blockIdx.y * 32, n0 = blockIdx.x * 32;
    int t = threadIdx.x;           // 256 threads
    int r = t >> 3, c4 = (t & 7) * 4;
    float4 v = *reinterpret_cast<const float4*>(src + (size_t)(k0 + r) * N + n0 + c4);
    tile[r][c4] = v.x; tile[r][c4 + 1] = v.y; tile[r][c4 + 2] = v.z; tile[r][c4 + 3] = v.w;
    __syncthreads();
    ushort4 o;
    o.x = f2bf(tile[c4][r]); o.y = f2bf(tile[c4 + 1][r]);
    o.z = f2bf(tile[c4 + 2][r]); o.w = f2bf(tile[c4 + 3][r]);
    *reinterpret_cast<ushort4*>(dst + (size_t)(n0 + r) * K + k0 + c4) = o;
}

// ---------------- combined bias: bias_tot[c] = b_fus[c] + sum_k bp[k]*Wf[768+k][c] ----------------
__global__ void k_bias_tot(const float* __restrict__ Wf, const float* __restrict__ bp,
                           const float* __restrict__ bfu, float* __restrict__ bias_tot) {
    int c = blockIdx.x * 256 + threadIdx.x;
    if (c >= ND) return;
    float acc = bfu[c];
#pragma unroll 8
    for (int k = 0; k < ND; k++) acc += bp[k] * Wf[(size_t)(ND + k) * ND + c];
    bias_tot[c] = acc;
}

// ---------------- a_src / a_dst: [B,H,S] dot of x with att vectors ----------------
__global__ void k_attn_vec(const unsigned short* __restrict__ x, const float* __restrict__ att_src,
                           const float* __restrict__ att_dst, float* __restrict__ a_src,
                           float* __restrict__ a_dst) {
    int bs = blockIdx.x;           // 0..B*S-1
    int c = threadIdx.x;           // 0..63
    int b = bs >> 10, s = bs & 1023;
    const unsigned short* xr = x + (size_t)bs * ND;
    float ps[NH], pd[NH];
#pragma unroll
    for (int h = 0; h < NH; h++) {
        float xv = bf2f(xr[h * 64 + c]);
        ps[h] = xv * att_src[h * 64 + c];
        pd[h] = xv * att_dst[h * 64 + c];
    }
#pragma unroll
    for (int off = 32; off >= 1; off >>= 1) {
#pragma unroll
        for (int h = 0; h < NH; h++) {
            ps[h] += __shfl_down(ps[h], off, 64);
            pd[h] += __shfl_down(pd[h], off, 64);
        }
    }
    if (c == 0) {
#pragma unroll
        for (int h = 0; h < NH; h++) {
            a_src[((size_t)b * NH + h) * NS + s] = ps[h];
            a_dst[((size_t)b * NH + h) * NS + s] = pd[h];
        }
    }
}

// ---------------- counting sort of a_src into NBUK buckets per (b,h) ----------------
// emits: pack[bh][pos] = (u, e^u, e^{0.2u}, bitcast(orig_idx)), bstart[bh][257], smax, {mn,scale}
__global__ __launch_bounds__(256) void k_bucket(const float* __restrict__ a_src,
                                                float4* __restrict__ pack,
                                                int* __restrict__ bstart,
                                                float* __restrict__ smax_g,
                                                float2* __restrict__ bparam) {
    int bh = blockIdx.x, t = threadIdx.x;
    __shared__ float v[1024];
    __shared__ int bi[1024];
    __shared__ float red[256];
    __shared__ int cnt[256];
    __shared__ int pre[256];
    for (int i = t; i < 1024; i += 256) v[i] = a_src[(size_t)bh * 1024 + i];
    cnt[t] = 0;
    __syncthreads();
    float lm = -1e30f, ln = 1e30f;
    for (int i = t; i < 1024; i += 256) { lm = fmaxf(lm, v[i]); ln = fminf(ln, v[i]); }
    red[t] = lm; __syncthreads();
    for (int s = 128; s > 0; s >>= 1) { if (t < s) red[t] = fmaxf(red[t], red[t + s]); __syncthreads(); }
    float mx = red[0]; __syncthreads();
    red[t] = ln; __syncthreads();
    for (int s = 128; s > 0; s >>= 1) { if (t < s) red[t] = fminf(red[t], red[t + s]); __syncthreads(); }
    float mn = red[0]; __syncthreads();
    float scale = (float)NBUK / fmaxf(mx - mn, 1e-20f);
    for (int i = t; i < 1024; i += 256) {
        int bk = (int)((v[i] - mn) * scale);
        bk = min(max(bk, 0), NBUK - 1);
        bi[i] = bk;
        atomicAdd(&cnt[bk], 1);
    }
    __syncthreads();
    pre[t] = cnt[t]; __syncthreads();
    for (int off = 1; off < 256; off <<= 1) {
        int x = (t >= off) ? pre[t - off] : 0;
        __syncthreads();
        pre[t] += x;
        __syncthreads();
    }
    int start = pre[t] - cnt[t];
    bstart[bh * 257 + t] = start;
    if (t == 0) {
        bstart[bh * 257 + 256] = 1024;
        smax_g[bh] = mx;
        bparam[bh] = make_float2(mn, scale);
    }
    __syncthreads();
    cnt[t] = start;   // running offsets
    __syncthreads();
    for (int i = t; i < 1024; i += 256) {
        int pos = atomicAdd(&cnt[bi[i]], 1);
        float u = v[i] - mx;
        float4 p;
        p.x = u; p.y = __expf(u); p.z = __expf(0.2f * u); p.w = __int_as_float(i);
        pack[(size_t)bh * 1024 + pos] = p;
    }
}

// ---------------- per-bucket vector sums (64 ch) + scalar sums ----------------
__global__ __launch_bounds__(256) void k_bsum(const unsigned short* __restrict__ x_bf,
                                              const float4* __restrict__ pack,
                                              const int* __restrict__ bstart,
                                              float* __restrict__ P, float* __restrict__ zb) {
    int grp = blockIdx.x, bh = blockIdx.y;
    int t = threadIdx.x, w = t >> 6, lane = t & 63;
    int b = bh / NH, h = bh % NH;
    const float4* pk = pack + (size_t)bh * 1024;
    const unsigned short* xb = x_bf + (size_t)b * NS * ND + h * 64 + lane;
#pragma unroll
    for (int r = 0; r < 2; r++) {
        int bk = grp * 8 + w * 2 + r;
        int ks = bstart[bh * 257 + bk], ke = bstart[bh * 257 + bk + 1];
        float V1 = 0.f, V2 = 0.f, z1 = 0.f, z2 = 0.f;
        for (int k = ks; k < ke; k++) {
            float4 p = pk[k];
            int j = __float_as_int(p.w);
            float xv = bf2f(xb[(size_t)j * ND]);
            V1 += p.y * xv; V2 += p.z * xv; z1 += p.y; z2 += p.z;
        }
        size_t o = ((size_t)(bh * NBUK + bk) * 2) * 64 + lane;
        P[o] = V1; P[o + 64] = V2;
        if (lane == 0) {
            zb[(size_t)(bh * NBUK + bk) * 2] = z1;
            zb[(size_t)(bh * NBUK + bk) * 2 + 1] = z2;
        }
    }
}

// ---------------- inclusive prefix over buckets: vectors (in P) + scalars (in zb) ----------------
__global__ __launch_bounds__(256) void k_bpref(float* __restrict__ P, float* __restrict__ zb) {
    int bh = blockIdx.x, t = threadIdx.x, w = t >> 6, lane = t & 63;
    __shared__ float segV[4][2][64];
    __shared__ float zsh[512];
    zsh[t] = zb[(size_t)(bh * NBUK + t) * 2];
    zsh[256 + t] = zb[(size_t)(bh * NBUK + t) * 2 + 1];
    __syncthreads();
    for (int off = 1; off < 256; off <<= 1) {
        float x1 = (t >= off) ? zsh[t - off] : 0.f;
        float x2 = (t >= off) ? zsh[256 + t - off] : 0.f;
        __syncthreads();
        zsh[t] += x1; zsh[256 + t] += x2;
        __syncthreads();
    }
    zb[(size_t)(bh * NBUK + t) * 2] = zsh[t];
    zb[(size_t)(bh * NBUK + t) * 2 + 1] = zsh[256 + t];
    size_t base = (size_t)bh * NBUK;
    float V1 = 0.f, V2 = 0.f;
    for (int g = 0; g < 8; ++g) {
        float a1[8], a2[8];
#pragma unroll
        for (int r = 0; r < 8; r++) {
            size_t o = ((base + w * 64 + g * 8 + r) * 2) * 64 + lane;
            a1[r] = P[o]; a2[r] = P[o + 64];
        }
#pragma unroll
        for (int r = 0; r < 8; r++) { V1 += a1[r]; a1[r] = V1; V2 += a2[r]; a2[r] = V2; }
#pragma unroll
        for (int r = 0; r < 8; r++) {
            size_t o = ((base + w * 64 + g * 8 + r) * 2) * 64 + lane;
            P[o] = a1[r]; P[o + 64] = a2[r];
        }
    }
    segV[w][0][lane] = V1; segV[w][1][lane] = V2;
    __syncthreads();
    if (w > 0) {
        float O1 = 0.f, O2 = 0.f;
        for (int w2 = 0; w2 < w; w2++) { O1 += segV[w2][0][lane]; O2 += segV[w2][1][lane]; }
        for (int g = 0; g < 8; ++g) {
            float a1[8], a2[8];
#pragma unroll
            for (int r = 0; r < 8; r++) {
                size_t o = ((base + w * 64 + g * 8 + r) * 2) * 64 + lane;
                a1[r] = P[o]; a2[r] = P[o + 64];
            }
#pragma unroll
            for (int r = 0; r < 8; r++) {
                size_t o = ((base + w * 64 + g * 8 + r) * 2) * 64 + lane;
                P[o] = a1[r] + O1; P[o + 64] = a2[r] + O2;
            }
        }
    }
}

// ---------------- apply: bucket lookup + partial-bucket exact test ----------------
__global__ __launch_bounds__(256) void k_apply3(const unsigned short* __restrict__ x_bf,
                                                const float4* __restrict__ pack,
                                                const int* __restrict__ bstart,
                                                const float* __restrict__ P,
                                                const float* __restrict__ zb,
                                                const float* __restrict__ a_dst,
                                                const float* __restrict__ smax_g,
                                                const float2* __restrict__ bparam,
                                                const float* __restrict__ b_gat,
                                                unsigned short* __restrict__ gat) {
    int bh = blockIdx.y, t = threadIdx.x, w = t >> 6, lane = t & 63;
    int b = bh / NH, h = bh % NH;
    float sm = smax_g[bh];
    float2 bp_ = bparam[bh];
    float mn = bp_.x, scale = bp_.y;
    size_t pb = (size_t)bh * NBUK;
    float T1 = P[((pb + NBUK - 1) * 2) * 64 + lane];
    float z1tot = zb[(pb + NBUK - 1) * 2];
    float z2tot = zb[(pb + NBUK - 1) * 2 + 1];
    float bias = b_gat[h * 64 + lane];
    const float4* pk = pack + (size_t)bh * 1024;
    const unsigned short* xb = x_bf + (size_t)b * NS * ND + h * 64 + lane;
#pragma unroll
    for (int q = 0; q < 8; q++) {
        int i = blockIdx.x * 32 + w * 8 + q;
        float d = a_dst[(size_t)bh * 1024 + i];
        float dm = d + sm;
        float m = dm > 0.f ? dm : NEG * dm;
        float c1 = __expf(dm - m);
        float c2 = __expf(NEG * dm - m);
        float vthr = -dm;
        int bi = (int)floorf((vthr - mn) * scale);
        bi = min(max(bi, 0), NBUK - 1);
        float P1f = 0.f, P2f = 0.f, z1f = 0.f, z2f = 0.f;
        if (bi > 0) {
            size_t o = ((pb + bi - 1) * 2) * 64 + lane;
            P1f = P[o]; P2f = P[o + 64];
            z1f = zb[(pb + bi - 1) * 2];
            z2f = zb[(pb + bi - 1) * 2 + 1];
        }
        int ks = bstart[bh * 257 + bi], ke = bstart[bh * 257 + bi + 1];
        float p1 = 0.f, p2 = 0.f, pz1 = 0.f, pz2 = 0.f;
        for (int k = ks; k < ke; k++) {
            float4 pkk = pk[k];
            if (pkk.x <= vthr) {
                int j = __float_as_int(pkk.w);
                float xv = bf2f(xb[(size_t)j * ND]);
                p1 += pkk.y * xv; p2 += pkk.z * xv; pz1 += pkk.y; pz2 += pkk.z;
            }
        }
        float num = c1 * (T1 - P1f - p1) + c2 * (P2f + p2);
        float Z = c1 * (z1tot - z1f - pz1) + c2 * (z2f + pz2);
        gat[((size_t)(b * NS + i)) * ND + h * 64 + lane] = f2bf(num / Z + bias);
    }
}

// ---------------- GEMM: C[M,N] = A[M,K] @ Bt[N,K]^T -> bf16 ----------------
__global__ __launch_bounds__(256) void k_gemm_bf(const unsigned short* __restrict__ A,
                                                 const unsigned short* __restrict__ Bt,
                                                 unsigned short* __restrict__ Cout,
                                                 int M, int N, int K, int lda, int ldb) {
    __shared__ alignas(16) unsigned short sA[128][40];
    __shared__ alignas(16) unsigned short sB[128][40];
    int m0 = blockIdx.y * 128, n0 = blockIdx.x * 128;
    int t = threadIdx.x;
    int wave = t >> 6, lane = t & 63;
    int wm = wave >> 1, wn = wave & 1;
    int lr = lane & 15, kg = (lane >> 4) * 8;
    f32x4 acc[4][4] = {};
    for (int k0 = 0; k0 < K; k0 += 32) {
        __syncthreads();
#pragma unroll
        for (int u = 0; u < 2; u++) {
            int idx = t + u * 256;
            int r = idx >> 2, sg = (idx & 3) * 8;
            *reinterpret_cast<bf16x8*>(&sA[r][sg]) =
                *reinterpret_cast<const bf16x8*>(A + (size_t)(m0 + r) * lda + k0 + sg);
            *reinterpret_cast<bf16x8*>(&sB[r][sg]) =
                *reinterpret_cast<const bf16x8*>(Bt + (size_t)(n0 + r) * ldb + k0 + sg);
        }
        __syncthreads();
        bf16x8 af[4], bfr[4];
#pragma unroll
        for (int m = 0; m < 4; m++) af[m] = *reinterpret_cast<bf16x8*>(&sA[wm * 64 + m * 16 + lr][kg]);
#pragma unroll
        for (int n = 0; n < 4; n++) bfr[n] = *reinterpret_cast<bf16x8*>(&sB[wn * 64 + n * 16 + lr][kg]);
#pragma unroll
        for (int m = 0; m < 4; m++)
#pragma unroll
            for (int n = 0; n < 4; n++)
                acc[m][n] = __builtin_amdgcn_mfma_f32_16x16x32_bf16(af[m], bfr[n], acc[m][n], 0, 0, 0);
    }
    int rg = (lane >> 4) * 4;
#pragma unroll
    for (int m = 0; m < 4; m++) {
#pragma unroll
        for (int n = 0; n < 4; n++) {
            int col = n0 + wn * 64 + n * 16 + lr;
#pragma unroll
            for (int r = 0; r < 4; r++) {
                int row = m0 + wm * 64 + m * 16 + rg + r;
                Cout[(size_t)row * N + col] = f2bf(acc[m][n][r]);
            }
        }
    }
}

// ---------------- dual GEMM: out = A1@B1t^T + A2@B2t^T + bias (fp32 out) ----------------
__global__ __launch_bounds__(256) void k_gemm_dual(const unsigned short* __restrict__ A1,
                                                   const unsigned short* __restrict__ B1t,
                                                   const unsigned short* __restrict__ A2,
                                                   const unsigned short* __restrict__ B2t,
                                                   const float* __restrict__ bias,
                                                   float* __restrict__ out) {
    __shared__ alignas(16) unsigned short sA[128][40];
    __shared__ alignas(16) unsigned short sB[128][40];
    int m0 = blockIdx.y * 128, n0 = blockIdx.x * 128;
    int t = threadIdx.x;
    int wave = t >> 6, lane = t & 63;
    int wm = wave >> 1, wn = wave & 1;
    int lr = lane & 15, kg = (lane >> 4) * 8;
    f32x4 acc[4][4] = {};
#pragma unroll
    for (int phase = 0; phase < 2; phase++) {
        const unsigned short* A = phase ? A2 : A1;
        const unsigned short* Bt = phase ? B2t : B1t;
        int ldb = phase ? ND : 2 * ND;
        for (int k0 = 0; k0 < ND; k0 += 32) {
            __syncthreads();
#pragma unroll
            for (int u = 0; u < 2; u++) {
                int idx = t + u * 256;
                int r = idx >> 2, sg = (idx & 3) * 8;
                *reinterpret_cast<bf16x8*>(&sA[r][sg]) =
                    *reinterpret_cast<const bf16x8*>(A + (size_t)(m0 + r) * ND + k0 + sg);
                *reinterpret_cast<bf16x8*>(&sB[r][sg]) =
                    *reinterpret_cast<const bf16x8*>(Bt + (size_t)(n0 + r) * ldb + k0 + sg);
            }
            __syncthreads();
            bf16x8 af[4], bfr[4];
#pragma unroll
            for (int m = 0; m < 4; m++) af[m] = *reinterpret_cast<bf16x8*>(&sA[wm * 64 + m * 16 + lr][kg]);
#pragma unroll
            for (int n = 0; n < 4; n++) bfr[n] = *reinterpret_cast<bf16x8*>(&sB[wn * 64 + n * 16 + lr][kg]);
#pragma unroll
            for (int m = 0; m < 4; m++)
#pragma unroll
                for (int n = 0; n < 4; n++)
                    acc[m][n] = __builtin_amdgcn_mfma_f32_16x16x32_bf16(af[m], bfr[n], acc[m][n], 0, 0, 0);
        }
    }
    int rg = (lane >> 4) * 4;
#pragma unroll
    for (int m = 0; m < 4; m++) {
#pragma unroll
        for (int n = 0; n < 4; n++) {
            int col = n0 + wn * 64 + n * 16 + lr;
            float bv = bias[col];
#pragma unroll
            for (int r = 0; r < 4; r++) {
                int row = m0 + wm * 64 + m * 16 + rg + r;
                out[(size_t)row * ND + col] = acc[m][n][r] + bv;
            }
        }
    }
}

extern "C" void kernel_launch(void* const* d_in, const int* in_sizes, int n_in,
                              void* d_out, int out_size, void* d_ws, size_t ws_size,
                              hipStream_t stream) {
    const float* hs  = (const float*)d_in[0];
    const float* to  = (const float*)d_in[1];
    const float* Wg  = (const float*)d_in[2];
    const float* asv = (const float*)d_in[3];
    const float* adv = (const float*)d_in[4];
    const float* bg  = (const float*)d_in[5];
    const float* Wp  = (const float*)d_in[6];
    const float* bp  = (const float*)d_in[7];
    const float* Wf  = (const float*)d_in[8];
    const float* bfu = (const float*)d_in[9];
    float* out = (float*)d_out;

    char* ws = (char*)d_ws;
    size_t off = 0;
    auto alloc = [&](size_t bytes) -> void* {
        void* p = ws + off;
        off = (off + bytes + 255) & ~(size_t)255;
        return p;
    };
    const size_t NBSD = (size_t)NB * NS * ND;
    const int NBH = NB * NH;
    unsigned short* h_bf   = (unsigned short*)alloc(NBSD * 2);  // later reused as gat_bf
    unsigned short* x_bf   = (unsigned short*)alloc(NBSD * 2);
    unsigned short* t_bf   = (unsigned short*)alloc(NBSD * 2);
    unsigned short* WgT    = (unsigned short*)alloc((size_t)ND * ND * 2);
    unsigned short* Wp_bf  = (unsigned short*)alloc((size_t)ND * ND * 2);
    unsigned short* WfT    = (unsigned short*)alloc((size_t)2 * ND * ND * 2);
    unsigned short* WcombT = (unsigned short*)alloc((size_t)ND * ND * 2);
    float*  bias_tot = (float*)alloc((size_t)ND * 4);
    float*  a_src = (float*)alloc((size_t)NBH * NS * 4);
    float*  a_dst = (float*)alloc((size_t)NBH * NS * 4);
    float4* pack  = (float4*)alloc((size_t)NBH * NS * 16);
    int*    bstart = (int*)alloc((size_t)NBH * 257 * 4);
    float*  P     = (float*)alloc((size_t)NBH * NBUK * 2 * 64 * 4);
    float*  zb    = (float*)alloc((size_t)NBH * NBUK * 2 * 4);
    float*  smaxb = (float*)alloc((size_t)NBH * 4);
    float2* bparam = (float2*)alloc((size_t)NBH * 8);

    int n = (int)NBSD;
    k_f32_to_bf16<<<n / 4 / 256, 256, 0, stream>>>(hs, h_bf, n);
    k_f32_to_bf16<<<n / 4 / 256, 256, 0, stream>>>(to, t_bf, n);
    k_f32_to_bf16<<<(ND * ND) / 4 / 256, 256, 0, stream>>>(Wp, Wp_bf, ND * ND);
    k_transpose_conv<<<dim3(ND / 32, ND / 32), 256, 0, stream>>>(Wg, WgT, ND, ND);
    k_transpose_conv<<<dim3(ND / 32, 2 * ND / 32), 256, 0, stream>>>(Wf, WfT, 2 * ND, ND);

    // WcombT = (Wp @ Wf_bot) transposed:  WcombT[n][k] = sum_r WfT[n][768+r] * Wp[k][r]
    k_gemm_bf<<<dim3(ND / 128, ND / 128), 256, 0, stream>>>(
        WfT + ND, Wp_bf, WcombT, ND, ND, ND, 2 * ND, ND);
    k_bias_tot<<<3, 256, 0, stream>>>(Wf, bp, bfu, bias_tot);

    // GEMM1: x = hs @ W_gat  -> bf16
    k_gemm_bf<<<dim3(ND / 128, NB * NS / 128), 256, 0, stream>>>(
        h_bf, WgT, x_bf, NB * NS, ND, ND, ND, ND);

    k_attn_vec<<<NB * NS, 64, 0, stream>>>(x_bf, asv, adv, a_src, a_dst);
    k_bucket<<<NBH, 256, 0, stream>>>(a_src, pack, bstart, smaxb, bparam);
    k_bsum<<<dim3(NBUK / 8, NBH), 256, 0, stream>>>(x_bf, pack, bstart, P, zb);
    k_bpref<<<NBH, 256, 0, stream>>>(P, zb);

    unsigned short* gat_bf = h_bf;
    k_apply3<<<dim3(NS / 32, NBH), 256, 0, stream>>>(x_bf, pack, bstart, P, zb, a_dst,
                                                     smaxb, bparam, bg, gat_bf);

    // out = t @ Wf_top + gat @ Wcomb + bias_tot
    k_gemm_dual<<<dim3(ND / 128, NB * NS / 128), 256, 0, stream>>>(
        t_bf, WfT, gat_bf, WcombT, bias_tot, out);
}

// Round 4
// 212.211 us; speedup vs baseline: 1.7091x; 1.2090x over previous
//
#include <hip/hip_runtime.h>
#include <hip/hip_bf16.h>

#define NB 8
#define NS 1024
#define ND 768
#define NH 12
#define NC 64
#define NEG 0.2f
#define NBUK 256

typedef __attribute__((ext_vector_type(8))) short bf16x8;
typedef __attribute__((ext_vector_type(4))) float f32x4;

static __device__ __forceinline__ float bf2f(unsigned short u) {
    union { float f; unsigned int i; } v; v.i = ((unsigned int)u) << 16; return v.f;
}
static __device__ __forceinline__ unsigned short f2bf(float f) {
    union { float f; unsigned int i; } v; v.f = f;
    unsigned int r = v.i + 0x7FFFu + ((v.i >> 16) & 1u);
    return (unsigned short)(r >> 16);
}

static __device__ __forceinline__ void gload16(const unsigned short* g, unsigned short* l) {
    __builtin_amdgcn_global_load_lds((const __attribute__((address_space(1))) void*)g,
                                     (__attribute__((address_space(3))) void*)l, 16, 0, 0);
}

// bijective XCD-chunk swizzle (m204)
static __device__ __forceinline__ int swz_bid(int orig, int nwg) {
    int q = nwg >> 3, r = nwg & 7;
    int xcd = orig & 7, idx = orig >> 3;
    return (xcd < r ? xcd * (q + 1) : r * (q + 1) + (xcd - r) * q) + idx;
}

// ---------------- fp32 -> bf16 elementwise convert ----------------
__global__ void k_f32_to_bf16(const float* __restrict__ src, unsigned short* __restrict__ dst, int n) {
    int i = (blockIdx.x * blockDim.x + threadIdx.x) * 4;
    if (i >= n) return;
    float4 v = *reinterpret_cast<const float4*>(src + i);
    ushort4 o;
    o.x = f2bf(v.x); o.y = f2bf(v.y); o.z = f2bf(v.z); o.w = f2bf(v.w);
    *reinterpret_cast<ushort4*>(dst + i) = o;
}

// two-array variant (hs, to) in one launch
__global__ void k_conv2(const float* __restrict__ a, const float* __restrict__ b,
                        unsigned short* __restrict__ oa, unsigned short* __restrict__ ob, int n4) {
    int gid = blockIdx.x * blockDim.x + threadIdx.x;
    const float* s = (gid < n4) ? a : b;
    unsigned short* d = (gid < n4) ? oa : ob;
    int i = ((gid < n4) ? gid : gid - n4) * 4;
    float4 v = *reinterpret_cast<const float4*>(s + i);
    ushort4 o;
    o.x = f2bf(v.x); o.y = f2bf(v.y); o.z = f2bf(v.z); o.w = f2bf(v.w);
    *reinterpret_cast<ushort4*>(d + i) = o;
}

// ---------------- fp32 [K,N] -> bf16 [N,K] transpose-convert ----------------
__global__ void k_transpose_conv(const float* __restrict__ src, unsigned short* __restrict__ dst,
                                 int K, int N) {
    __shared__ float tile[32][33];
    int k0 = blockIdx.y * 32, n0 = blockIdx.x * 32;
    int t = threadIdx.x;           // 256 threads
    int r = t >> 3, c4 = (t & 7) * 4;
    float4 v = *reinterpret_cast<const float4*>(src + (size_t)(k0 + r) * N + n0 + c4);
    tile[r][c4] = v.x; tile[r][c4 + 1] = v.y; tile[r][c4 + 2] = v.z; tile[r][c4 + 3] = v.w;
    __syncthreads();
    ushort4 o;
    o.x = f2bf(tile[c4][r]); o.y = f2bf(tile[c4 + 1][r]);
    o.z = f2bf(tile[c4 + 2][r]); o.w = f2bf(tile[c4 + 3][r]);
    *reinterpret_cast<ushort4*>(dst + (size_t)(n0 + r) * K + k0 + c4) = o;
}

// ---------------- combined bias: bias_tot[c] = b_fus[c] + sum_k bp[k]*Wf[768+k][c] ----------------
__global__ void k_bias_tot(const float* __restrict__ Wf, const float* __restrict__ bp,
                           const float* __restrict__ bfu, float* __restrict__ bias_tot) {
    int gid = blockIdx.x * 256 + threadIdx.x;   // 24 blocks: (c, slice)
    int c = gid >> 3, sl = gid & 7;
    float acc = 0.f;
    int k0 = sl * 96;
#pragma unroll 8
    for (int k = k0; k < k0 + 96; k++) acc += bp[k] * Wf[(size_t)(ND + k) * ND + c];
    acc += __shfl_down(acc, 1, 64);
    acc += __shfl_down(acc, 2, 64);
    acc += __shfl_down(acc, 4, 64);
    if (sl == 0) bias_tot[c] = acc + bfu[c];
}

// ---------------- a_src / a_dst: thread-per-(row,head), no shuffles ----------------
__global__ __launch_bounds__(192) void k_attn_vec(const unsigned short* __restrict__ x,
                                                  const float* __restrict__ att_src,
                                                  const float* __restrict__ att_dst,
                                                  float* __restrict__ a_src,
                                                  float* __restrict__ a_dst) {
    __shared__ float s_src[ND], s_dst[ND];
    int t = threadIdx.x;
    for (int i = t; i < ND; i += 192) { s_src[i] = att_src[i]; s_dst[i] = att_dst[i]; }
    __syncthreads();
    int rl = t / 12, h = t - rl * 12;
    int bs = blockIdx.x * 16 + rl;
    const unsigned short* xr = x + (size_t)bs * ND + h * 64;
    float ps = 0.f, pd = 0.f;
#pragma unroll
    for (int j0 = 0; j0 < 64; j0 += 8) {
        bf16x8 v = *reinterpret_cast<const bf16x8*>(xr + j0);
#pragma unroll
        for (int j = 0; j < 8; j++) {
            float xv = bf2f((unsigned short)v[j]);
            ps = fmaf(xv, s_src[h * 64 + j0 + j], ps);
            pd = fmaf(xv, s_dst[h * 64 + j0 + j], pd);
        }
    }
    int b = bs >> 10, s = bs & 1023;
    a_src[((size_t)b * NH + h) * NS + s] = ps;
    a_dst[((size_t)b * NH + h) * NS + s] = pd;
}

// ---------------- counting sort into NBUK buckets; emits pack, bstart, smax, bparam,
//                  and INCLUSIVE scalar prefix zb (z-scan fused here) ----------------
__global__ __launch_bounds__(256) void k_bucket(const float* __restrict__ a_src,
                                                float4* __restrict__ pack,
                                                int* __restrict__ bstart,
                                                float* __restrict__ smax_g,
                                                float2* __restrict__ bparam,
                                                float* __restrict__ zb) {
    int bh = blockIdx.x, t = threadIdx.x;
    __shared__ float v[1024];
    __shared__ int bi[1024];
    __shared__ float red[256];
    __shared__ int cnt[256];
    __shared__ int pre[256];
    __shared__ float zs1[256], zs2[256];
    for (int i = t; i < 1024; i += 256) v[i] = a_src[(size_t)bh * 1024 + i];
    cnt[t] = 0; zs1[t] = 0.f; zs2[t] = 0.f;
    __syncthreads();
    float lm = -1e30f, ln = 1e30f;
    for (int i = t; i < 1024; i += 256) { lm = fmaxf(lm, v[i]); ln = fminf(ln, v[i]); }
    red[t] = lm; __syncthreads();
    for (int s = 128; s > 0; s >>= 1) { if (t < s) red[t] = fmaxf(red[t], red[t + s]); __syncthreads(); }
    float mx = red[0]; __syncthreads();
    red[t] = ln; __syncthreads();
    for (int s = 128; s > 0; s >>= 1) { if (t < s) red[t] = fminf(red[t], red[t + s]); __syncthreads(); }
    float mn = red[0]; __syncthreads();
    float scale = (float)NBUK / fmaxf(mx - mn, 1e-20f);
    for (int i = t; i < 1024; i += 256) {
        int bk = (int)((v[i] - mn) * scale);
        bk = min(max(bk, 0), NBUK - 1);
        bi[i] = bk;
        atomicAdd(&cnt[bk], 1);
    }
    __syncthreads();
    pre[t] = cnt[t]; __syncthreads();
    for (int off = 1; off < 256; off <<= 1) {
        int x = (t >= off) ? pre[t - off] : 0;
        __syncthreads();
        pre[t] += x;
        __syncthreads();
    }
    int start = pre[t] - cnt[t];
    bstart[bh * 257 + t] = start;
    if (t == 0) {
        bstart[bh * 257 + 256] = 1024;
        smax_g[bh] = mx;
        bparam[bh] = make_float2(mn, scale);
    }
    __syncthreads();
    cnt[t] = start;   // running offsets
    __syncthreads();
    for (int i = t; i < 1024; i += 256) {
        int pos = atomicAdd(&cnt[bi[i]], 1);
        float u = v[i] - mx;
        float4 p;
        p.x = u; p.y = __expf(u); p.z = __expf(0.2f * u); p.w = __int_as_float(i);
        pack[(size_t)bh * 1024 + pos] = p;
        atomicAdd(&zs1[bi[i]], p.y);
        atomicAdd(&zs2[bi[i]], p.z);
    }
    __syncthreads();
    float z1v = zs1[t], z2v = zs2[t];
    red[t] = z1v;   // reuse red for scan of z1
    __syncthreads();
    for (int off = 1; off < 256; off <<= 1) {
        float x1 = (t >= off) ? red[t - off] : 0.f;
        float x2 = (t >= off) ? zs2[t - off] : 0.f;
        __syncthreads();
        red[t] += x1; zs2[t] += x2;
        __syncthreads();
    }
    zb[(size_t)(bh * NBUK + t) * 2] = red[t];
    zb[(size_t)(bh * NBUK + t) * 2 + 1] = zs2[t];
}

// ---------------- per-bucket vector sums (64 ch) ----------------
__global__ __launch_bounds__(256) void k_bsum(const unsigned short* __restrict__ x_bf,
                                              const float4* __restrict__ pack,
                                              const int* __restrict__ bstart,
                                              float* __restrict__ P) {
    int grp = blockIdx.x, bh = blockIdx.y;
    int t = threadIdx.x, w = t >> 6, lane = t & 63;
    int b = bh / NH, h = bh % NH;
    const float4* pk = pack + (size_t)bh * 1024;
    const unsigned short* xb = x_bf + (size_t)b * NS * ND + h * 64 + lane;
#pragma unroll
    for (int r = 0; r < 2; r++) {
        int bk = grp * 8 + w * 2 + r;
        int ks = bstart[bh * 257 + bk], ke = bstart[bh * 257 + bk + 1];
        float V1 = 0.f, V2 = 0.f;
        for (int k = ks; k < ke; k++) {
            float4 p = pk[k];
            int j = __float_as_int(p.w);
            float xv = bf2f(xb[(size_t)j * ND]);
            V1 += p.y * xv; V2 += p.z * xv;
        }
        size_t o = ((size_t)(bh * NBUK + bk) * 2) * 64 + lane;
        P[o] = V1; P[o + 64] = V2;
    }
}

// ---------------- inclusive prefix over buckets for vectors P ----------------
__global__ __launch_bounds__(256) void k_bpref(float* __restrict__ P) {
    int bh = blockIdx.x, t = threadIdx.x, w = t >> 6, lane = t & 63;
    __shared__ float segV[4][2][64];
    size_t base = (size_t)bh * NBUK;
    float V1 = 0.f, V2 = 0.f;
    for (int g = 0; g < 8; ++g) {
        float a1[8], a2[8];
#pragma unroll
        for (int r = 0; r < 8; r++) {
            size_t o = ((base + w * 64 + g * 8 + r) * 2) * 64 + lane;
            a1[r] = P[o]; a2[r] = P[o + 64];
        }
#pragma unroll
        for (int r = 0; r < 8; r++) { V1 += a1[r]; a1[r] = V1; V2 += a2[r]; a2[r] = V2; }
#pragma unroll
        for (int r = 0; r < 8; r++) {
            size_t o = ((base + w * 64 + g * 8 + r) * 2) * 64 + lane;
            P[o] = a1[r]; P[o + 64] = a2[r];
        }
    }
    segV[w][0][lane] = V1; segV[w][1][lane] = V2;
    __syncthreads();
    if (w > 0) {
        float O1 = 0.f, O2 = 0.f;
        for (int w2 = 0; w2 < w; w2++) { O1 += segV[w2][0][lane]; O2 += segV[w2][1][lane]; }
        for (int g = 0; g < 8; ++g) {
            float a1[8], a2[8];
#pragma unroll
            for (int r = 0; r < 8; r++) {
                size_t o = ((base + w * 64 + g * 8 + r) * 2) * 64 + lane;
                a1[r] = P[o]; a2[r] = P[o + 64];
            }
#pragma unroll
            for (int r = 0; r < 8; r++) {
                size_t o = ((base + w * 64 + g * 8 + r) * 2) * 64 + lane;
                P[o] = a1[r] + O1; P[o + 64] = a2[r] + O2;
            }
        }
    }
}

// ---------------- apply: bucket lookup + partial-bucket exact test ----------------
__global__ __launch_bounds__(256) void k_apply3(const unsigned short* __restrict__ x_bf,
                                                const float4* __restrict__ pack,
                                                const int* __restrict__ bstart,
                                                const float* __restrict__ P,
                                                const float* __restrict__ zb,
                                                const float* __restrict__ a_dst,
                                                const float* __restrict__ smax_g,
                                                const float2* __restrict__ bparam,
                                                const float* __restrict__ b_gat,
                                                unsigned short* __restrict__ gat) {
    int bh = blockIdx.y, t = threadIdx.x, w = t >> 6, lane = t & 63;
    int b = bh / NH, h = bh % NH;
    float sm = smax_g[bh];
    float2 bp_ = bparam[bh];
    float mn = bp_.x, scale = bp_.y;
    size_t pb = (size_t)bh * NBUK;
    float T1 = P[((pb + NBUK - 1) * 2) * 64 + lane];
    float z1tot = zb[(pb + NBUK - 1) * 2];
    float bias = b_gat[h * 64 + lane];
    const float4* pk = pack + (size_t)bh * 1024;
    const unsigned short* xb = x_bf + (size_t)b * NS * ND + h * 64 + lane;
#pragma unroll
    for (int q = 0; q < 8; q++) {
        int i = blockIdx.x * 32 + w * 8 + q;
        float d = a_dst[(size_t)bh * 1024 + i];
        float dm = d + sm;
        float m = dm > 0.f ? dm : NEG * dm;
        float c1 = __expf(dm - m);
        float c2 = __expf(NEG * dm - m);
        float vthr = -dm;
        int bi = (int)floorf((vthr - mn) * scale);
        bi = min(max(bi, 0), NBUK - 1);
        float P1f = 0.f, P2f = 0.f, z1f = 0.f, z2f = 0.f;
        if (bi > 0) {
            size_t o = ((pb + bi - 1) * 2) * 64 + lane;
            P1f = P[o]; P2f = P[o + 64];
            z1f = zb[(pb + bi - 1) * 2];
            z2f = zb[(pb + bi - 1) * 2 + 1];
        }
        int ks = bstart[bh * 257 + bi], ke = bstart[bh * 257 + bi + 1];
        float p1 = 0.f, p2 = 0.f, pz1 = 0.f, pz2 = 0.f;
        for (int k = ks; k < ke; k++) {
            float4 pkk = pk[k];
            if (pkk.x <= vthr) {
                int j = __float_as_int(pkk.w);
                float xv = bf2f(xb[(size_t)j * ND]);
                p1 += pkk.y * xv; p2 += pkk.z * xv; pz1 += pkk.y; pz2 += pkk.z;
            }
        }
        float num = c1 * (T1 - P1f - p1) + c2 * (P2f + p2);
        float Z = c1 * (z1tot - z1f - pz1) + c2 * (zb[(pb + bi - 1 < pb ? pb : pb + bi - 1) * 2 + 1] * 0.f + z2f + pz2);
        gat[((size_t)(b * NS + i)) * ND + h * 64 + lane] = f2bf(num / Z + bias);
    }
}

// ---------------- GEMM (m97 structure): C = A1@B1t^T [+ A2@B2t^T] [+bias] ----------------
// linear LDS [128][32], global_load_lds 16B staging, 2-barrier K-loop,
// m-fastest logical grid + bijective XCD swizzle.
template <bool DUAL, bool OUT_BF16, bool BIAS>
__global__ __launch_bounds__(256) void k_gemm2(const unsigned short* __restrict__ A1,
                                               const unsigned short* __restrict__ B1,
                                               const unsigned short* __restrict__ A2,
                                               const unsigned short* __restrict__ B2,
                                               const float* __restrict__ bias,
                                               void* __restrict__ Cout,
                                               int MB, int N, int K,
                                               int lda, int ldb1, int ldb2) {
    __shared__ alignas(16) unsigned short sA[128 * 32];
    __shared__ alignas(16) unsigned short sB[128 * 32];
    int nwg = gridDim.x;
    int wg = swz_bid(blockIdx.x, nwg);
    int m0 = (wg % MB) * 128, n0 = (wg / MB) * 128;
    int t = threadIdx.x;
    int wave = t >> 6, lane = t & 63;
    int wm = wave >> 1, wn = wave & 1;
    int lr = lane & 15, kg = (lane >> 4) * 8;
    int srow = t >> 2, scol = (t & 3) * 8;
    unsigned short* lA1 = &sA[t * 8];
    unsigned short* lA2 = &sA[2048 + t * 8];
    unsigned short* lB1 = &sB[t * 8];
    unsigned short* lB2 = &sB[2048 + t * 8];
    f32x4 acc[4][4] = {};
#pragma unroll 1
    for (int phase = 0; phase < (DUAL ? 2 : 1); phase++) {
        const unsigned short* A = (DUAL && phase) ? A2 : A1;
        const unsigned short* Bt = (DUAL && phase) ? B2 : B1;
        int ldb = (DUAL && phase) ? ldb2 : ldb1;
        const unsigned short* gA1 = A + (size_t)(m0 + srow) * lda + scol;
        const unsigned short* gA2 = gA1 + (size_t)64 * lda;
        const unsigned short* gB1 = Bt + (size_t)(n0 + srow) * ldb + scol;
        const unsigned short* gB2 = gB1 + (size_t)64 * ldb;
        for (int k0 = 0; k0 < K; k0 += 32) {
            __syncthreads();
            gload16(gA1 + k0, lA1);
            gload16(gA2 + k0, lA2);
            gload16(gB1 + k0, lB1);
            gload16(gB2 + k0, lB2);
            __syncthreads();
            bf16x8 af[4], bfr[4];
#pragma unroll
            for (int m = 0; m < 4; m++)
                af[m] = *reinterpret_cast<bf16x8*>(&sA[(wm * 64 + m * 16 + lr) * 32 + kg]);
#pragma unroll
            for (int n = 0; n < 4; n++)
                bfr[n] = *reinterpret_cast<bf16x8*>(&sB[(wn * 64 + n * 16 + lr) * 32 + kg]);
#pragma unroll
            for (int m = 0; m < 4; m++)
#pragma unroll
                for (int n = 0; n < 4; n++)
                    acc[m][n] = __builtin_amdgcn_mfma_f32_16x16x32_bf16(af[m], bfr[n], acc[m][n], 0, 0, 0);
        }
    }
    int rg = (lane >> 4) * 4;
#pragma unroll
    for (int m = 0; m < 4; m++) {
#pragma unroll
        for (int n = 0; n < 4; n++) {
            int col = n0 + wn * 64 + n * 16 + lr;
            float bv = BIAS ? bias[col] : 0.0f;
#pragma unroll
            for (int r = 0; r < 4; r++) {
                int row = m0 + wm * 64 + m * 16 + rg + r;
                float v = acc[m][n][r] + bv;
                if (OUT_BF16) {
                    ((unsigned short*)Cout)[(size_t)row * N + col] = f2bf(v);
                } else {
                    ((float*)Cout)[(size_t)row * N + col] = v;
                }
            }
        }
    }
}

extern "C" void kernel_launch(void* const* d_in, const int* in_sizes, int n_in,
                              void* d_out, int out_size, void* d_ws, size_t ws_size,
                              hipStream_t stream) {
    const float* hs  = (const float*)d_in[0];
    const float* to  = (const float*)d_in[1];
    const float* Wg  = (const float*)d_in[2];
    const float* asv = (const float*)d_in[3];
    const float* adv = (const float*)d_in[4];
    const float* bg  = (const float*)d_in[5];
    const float* Wp  = (const float*)d_in[6];
    const float* bp  = (const float*)d_in[7];
    const float* Wf  = (const float*)d_in[8];
    const float* bfu = (const float*)d_in[9];
    float* out = (float*)d_out;

    char* ws = (char*)d_ws;
    size_t off = 0;
    auto alloc = [&](size_t bytes) -> void* {
        void* p = ws + off;
        off = (off + bytes + 255) & ~(size_t)255;
        return p;
    };
    const size_t NBSD = (size_t)NB * NS * ND;
    const int NBH = NB * NH;
    unsigned short* h_bf   = (unsigned short*)alloc(NBSD * 2);  // later reused as gat_bf
    unsigned short* x_bf   = (unsigned short*)alloc(NBSD * 2);
    unsigned short* t_bf   = (unsigned short*)alloc(NBSD * 2);
    unsigned short* WgT    = (unsigned short*)alloc((size_t)ND * ND * 2);
    unsigned short* Wp_bf  = (unsigned short*)alloc((size_t)ND * ND * 2);
    unsigned short* WfT    = (unsigned short*)alloc((size_t)2 * ND * ND * 2);
    unsigned short* WcombT = (unsigned short*)alloc((size_t)ND * ND * 2);
    float*  bias_tot = (float*)alloc((size_t)ND * 4);
    float*  a_src = (float*)alloc((size_t)NBH * NS * 4);
    float*  a_dst = (float*)alloc((size_t)NBH * NS * 4);
    float4* pack  = (float4*)alloc((size_t)NBH * NS * 16);
    int*    bstart = (int*)alloc((size_t)NBH * 257 * 4);
    float*  P     = (float*)alloc((size_t)NBH * NBUK * 2 * 64 * 4);
    float*  zb    = (float*)alloc((size_t)NBH * NBUK * 2 * 4);
    float*  smaxb = (float*)alloc((size_t)NBH * 4);
    float2* bparam = (float2*)alloc((size_t)NBH * 8);

    int n = (int)NBSD;
    k_conv2<<<2 * (n / 4) / 256, 256, 0, stream>>>(hs, to, h_bf, t_bf, n / 4);
    k_f32_to_bf16<<<(ND * ND) / 4 / 256, 256, 0, stream>>>(Wp, Wp_bf, ND * ND);
    k_transpose_conv<<<dim3(ND / 32, ND / 32), 256, 0, stream>>>(Wg, WgT, ND, ND);
    k_transpose_conv<<<dim3(ND / 32, 2 * ND / 32), 256, 0, stream>>>(Wf, WfT, 2 * ND, ND);

    // WcombT = (Wp @ Wf_bot)^T : WcombT[n][k] = sum_r WfT[n][768+r] * Wp_bf[k][r]
    k_gemm2<false, true, false><<<(ND / 128) * (ND / 128), 256, 0, stream>>>(
        WfT + ND, Wp_bf, nullptr, nullptr, nullptr, WcombT, ND / 128, ND, ND, 2 * ND, ND, 0);
    k_bias_tot<<<ND * 8 / 256, 256, 0, stream>>>(Wf, bp, bfu, bias_tot);

    // GEMM1: x = hs @ W_gat  -> bf16
    k_gemm2<false, true, false><<<(NB * NS / 128) * (ND / 128), 256, 0, stream>>>(
        h_bf, WgT, nullptr, nullptr, nullptr, x_bf, NB * NS / 128, ND, ND, ND, ND, 0);

    k_attn_vec<<<NB * NS / 16, 192, 0, stream>>>(x_bf, asv, adv, a_src, a_dst);
    k_bucket<<<NBH, 256, 0, stream>>>(a_src, pack, bstart, smaxb, bparam, zb);
    k_bsum<<<dim3(NBUK / 8, NBH), 256, 0, stream>>>(x_bf, pack, bstart, P);
    k_bpref<<<NBH, 256, 0, stream>>>(P);

    unsigned short* gat_bf = h_bf;
    k_apply3<<<dim3(NS / 32, NBH), 256, 0, stream>>>(x_bf, pack, bstart, P, zb, a_dst,
                                                     smaxb, bparam, bg, gat_bf);

    // out = t @ Wf_top + gat @ Wcomb + bias_tot
    k_gemm2<true, false, true><<<(NB * NS / 128) * (ND / 128), 256, 0, stream>>>(
        t_bf, WfT, gat_bf, WcombT, bias_tot, out, NB * NS / 128, ND, ND, ND, 2 * ND, ND);
}

// Round 5
// 184.493 us; speedup vs baseline: 1.9659x; 1.1502x over previous
//
#include <hip/hip_runtime.h>
#include <hip/hip_bf16.h>

#define NB 8
#define NS 1024
#define ND 768
#define NH 12
#define NC 64
#define NEG 0.2f
#define NBUK 256

typedef __attribute__((ext_vector_type(8))) short bf16x8;
typedef __attribute__((ext_vector_type(4))) float f32x4;

static __device__ __forceinline__ float bf2f(unsigned short u) {
    union { float f; unsigned int i; } v; v.i = ((unsigned int)u) << 16; return v.f;
}
static __device__ __forceinline__ unsigned short f2bf(float f) {
    union { float f; unsigned int i; } v; v.f = f;
    unsigned int r = v.i + 0x7FFFu + ((v.i >> 16) & 1u);
    return (unsigned short)(r >> 16);
}

static __device__ __forceinline__ void gload16(const unsigned short* g, unsigned short* l) {
    __builtin_amdgcn_global_load_lds((const __attribute__((address_space(1))) void*)g,
                                     (__attribute__((address_space(3))) void*)l, 16, 0, 0);
}

// bijective XCD-chunk swizzle (m204)
static __device__ __forceinline__ int swz_bid(int orig, int nwg) {
    int q = nwg >> 3, r = nwg & 7;
    int xcd = orig & 7, idx = orig >> 3;
    return (xcd < r ? xcd * (q + 1) : r * (q + 1) + (xcd - r) * q) + idx;
}

// ---------------- fp32 -> bf16 elementwise convert ----------------
__global__ void k_f32_to_bf16(const float* __restrict__ src, unsigned short* __restrict__ dst, int n) {
    int i = (blockIdx.x * blockDim.x + threadIdx.x) * 4;
    if (i >= n) return;
    float4 v = *reinterpret_cast<const float4*>(src + i);
    ushort4 o;
    o.x = f2bf(v.x); o.y = f2bf(v.y); o.z = f2bf(v.z); o.w = f2bf(v.w);
    *reinterpret_cast<ushort4*>(dst + i) = o;
}

// two-array variant (hs, to) in one launch
__global__ void k_conv2(const float* __restrict__ a, const float* __restrict__ b,
                        unsigned short* __restrict__ oa, unsigned short* __restrict__ ob, int n4) {
    int gid = blockIdx.x * blockDim.x + threadIdx.x;
    const float* s = (gid < n4) ? a : b;
    unsigned short* d = (gid < n4) ? oa : ob;
    int i = ((gid < n4) ? gid : gid - n4) * 4;
    float4 v = *reinterpret_cast<const float4*>(s + i);
    ushort4 o;
    o.x = f2bf(v.x); o.y = f2bf(v.y); o.z = f2bf(v.z); o.w = f2bf(v.w);
    *reinterpret_cast<ushort4*>(d + i) = o;
}

// ---------------- fp32 [K,N] -> bf16 [N,K] transpose-convert ----------------
__global__ void k_transpose_conv(const float* __restrict__ src, unsigned short* __restrict__ dst,
                                 int K, int N) {
    __shared__ float tile[32][33];
    int k0 = blockIdx.y * 32, n0 = blockIdx.x * 32;
    int t = threadIdx.x;           // 256 threads
    int r = t >> 3, c4 = (t & 7) * 4;
    float4 v = *reinterpret_cast<const float4*>(src + (size_t)(k0 + r) * N + n0 + c4);
    tile[r][c4] = v.x; tile[r][c4 + 1] = v.y; tile[r][c4 + 2] = v.z; tile[r][c4 + 3] = v.w;
    __syncthreads();
    ushort4 o;
    o.x = f2bf(tile[c4][r]); o.y = f2bf(tile[c4 + 1][r]);
    o.z = f2bf(tile[c4 + 2][r]); o.w = f2bf(tile[c4 + 3][r]);
    *reinterpret_cast<ushort4*>(dst + (size_t)(n0 + r) * K + k0 + c4) = o;
}

// ---------------- combined bias: bias_tot[c] = b_fus[c] + sum_k bp[k]*Wf[768+k][c] ----------------
__global__ void k_bias_tot(const float* __restrict__ Wf, const float* __restrict__ bp,
                           const float* __restrict__ bfu, float* __restrict__ bias_tot) {
    int gid = blockIdx.x * 256 + threadIdx.x;   // 24 blocks: (c, slice)
    int c = gid >> 3, sl = gid & 7;
    float acc = 0.f;
    int k0 = sl * 96;
#pragma unroll 8
    for (int k = k0; k < k0 + 96; k++) acc += bp[k] * Wf[(size_t)(ND + k) * ND + c];
    acc += __shfl_down(acc, 1, 64);
    acc += __shfl_down(acc, 2, 64);
    acc += __shfl_down(acc, 4, 64);
    if (sl == 0) bias_tot[c] = acc + bfu[c];
}

// ---------------- a_src / a_dst: thread-per-(row,head), no shuffles ----------------
__global__ __launch_bounds__(192) void k_attn_vec(const unsigned short* __restrict__ x,
                                                  const float* __restrict__ att_src,
                                                  const float* __restrict__ att_dst,
                                                  float* __restrict__ a_src,
                                                  float* __restrict__ a_dst) {
    __shared__ float s_src[ND], s_dst[ND];
    int t = threadIdx.x;
    for (int i = t; i < ND; i += 192) { s_src[i] = att_src[i]; s_dst[i] = att_dst[i]; }
    __syncthreads();
    int rl = t / 12, h = t - rl * 12;
    int bs = blockIdx.x * 16 + rl;
    const unsigned short* xr = x + (size_t)bs * ND + h * 64;
    float ps = 0.f, pd = 0.f;
#pragma unroll
    for (int j0 = 0; j0 < 64; j0 += 8) {
        bf16x8 v = *reinterpret_cast<const bf16x8*>(xr + j0);
#pragma unroll
        for (int j = 0; j < 8; j++) {
            float xv = bf2f((unsigned short)v[j]);
            ps = fmaf(xv, s_src[h * 64 + j0 + j], ps);
            pd = fmaf(xv, s_dst[h * 64 + j0 + j], pd);
        }
    }
    int b = bs >> 10, s = bs & 1023;
    a_src[((size_t)b * NH + h) * NS + s] = ps;
    a_dst[((size_t)b * NH + h) * NS + s] = pd;
}

// ---------------- counting sort into NBUK buckets; emits pack, bstart, smax, bparam,
//                  and INCLUSIVE scalar prefix zb (z-scan fused here) ----------------
__global__ __launch_bounds__(256) void k_bucket(const float* __restrict__ a_src,
                                                float4* __restrict__ pack,
                                                int* __restrict__ bstart,
                                                float* __restrict__ smax_g,
                                                float2* __restrict__ bparam,
                                                float* __restrict__ zb) {
    int bh = blockIdx.x, t = threadIdx.x;
    __shared__ float v[1024];
    __shared__ int bi[1024];
    __shared__ float red[256];
    __shared__ int cnt[256];
    __shared__ int pre[256];
    __shared__ float zs1[256], zs2[256];
    for (int i = t; i < 1024; i += 256) v[i] = a_src[(size_t)bh * 1024 + i];
    cnt[t] = 0; zs1[t] = 0.f; zs2[t] = 0.f;
    __syncthreads();
    float lm = -1e30f, ln = 1e30f;
    for (int i = t; i < 1024; i += 256) { lm = fmaxf(lm, v[i]); ln = fminf(ln, v[i]); }
    red[t] = lm; __syncthreads();
    for (int s = 128; s > 0; s >>= 1) { if (t < s) red[t] = fmaxf(red[t], red[t + s]); __syncthreads(); }
    float mx = red[0]; __syncthreads();
    red[t] = ln; __syncthreads();
    for (int s = 128; s > 0; s >>= 1) { if (t < s) red[t] = fminf(red[t], red[t + s]); __syncthreads(); }
    float mn = red[0]; __syncthreads();
    float scale = (float)NBUK / fmaxf(mx - mn, 1e-20f);
    for (int i = t; i < 1024; i += 256) {
        int bk = (int)((v[i] - mn) * scale);
        bk = min(max(bk, 0), NBUK - 1);
        bi[i] = bk;
        atomicAdd(&cnt[bk], 1);
    }
    __syncthreads();
    pre[t] = cnt[t]; __syncthreads();
    for (int off = 1; off < 256; off <<= 1) {
        int x = (t >= off) ? pre[t - off] : 0;
        __syncthreads();
        pre[t] += x;
        __syncthreads();
    }
    int start = pre[t] - cnt[t];
    bstart[bh * 257 + t] = start;
    if (t == 0) {
        bstart[bh * 257 + 256] = 1024;
        smax_g[bh] = mx;
        bparam[bh] = make_float2(mn, scale);
    }
    __syncthreads();
    cnt[t] = start;   // running offsets
    __syncthreads();
    for (int i = t; i < 1024; i += 256) {
        int pos = atomicAdd(&cnt[bi[i]], 1);
        float u = v[i] - mx;
        float4 p;
        p.x = u; p.y = __expf(u); p.z = __expf(0.2f * u); p.w = __int_as_float(i);
        pack[(size_t)bh * 1024 + pos] = p;
        atomicAdd(&zs1[bi[i]], p.y);
        atomicAdd(&zs2[bi[i]], p.z);
    }
    __syncthreads();
    float z1v = zs1[t];
    red[t] = z1v;   // reuse red for scan of z1
    __syncthreads();
    for (int off = 1; off < 256; off <<= 1) {
        float x1 = (t >= off) ? red[t - off] : 0.f;
        float x2 = (t >= off) ? zs2[t - off] : 0.f;
        __syncthreads();
        red[t] += x1; zs2[t] += x2;
        __syncthreads();
    }
    zb[(size_t)(bh * NBUK + t) * 2] = red[t];
    zb[(size_t)(bh * NBUK + t) * 2 + 1] = zs2[t];
}

// ---------------- per-bucket vector sums (64 ch) ----------------
__global__ __launch_bounds__(256) void k_bsum(const unsigned short* __restrict__ x_bf,
                                              const float4* __restrict__ pack,
                                              const int* __restrict__ bstart,
                                              float* __restrict__ P) {
    int grp = blockIdx.x, bh = blockIdx.y;
    int t = threadIdx.x, w = t >> 6, lane = t & 63;
    int b = bh / NH, h = bh % NH;
    const float4* pk = pack + (size_t)bh * 1024;
    const unsigned short* xb = x_bf + (size_t)b * NS * ND + h * 64 + lane;
#pragma unroll
    for (int r = 0; r < 2; r++) {
        int bk = grp * 8 + w * 2 + r;
        int ks = bstart[bh * 257 + bk], ke = bstart[bh * 257 + bk + 1];
        float V1 = 0.f, V2 = 0.f;
        for (int k = ks; k < ke; k++) {
            float4 p = pk[k];
            int j = __float_as_int(p.w);
            float xv = bf2f(xb[(size_t)j * ND]);
            V1 += p.y * xv; V2 += p.z * xv;
        }
        size_t o = ((size_t)(bh * NBUK + bk) * 2) * 64 + lane;
        P[o] = V1; P[o + 64] = V2;
    }
}

// ---------------- inclusive prefix over buckets for vectors P ----------------
__global__ __launch_bounds__(256) void k_bpref(float* __restrict__ P) {
    int bh = blockIdx.x, t = threadIdx.x, w = t >> 6, lane = t & 63;
    __shared__ float segV[4][2][64];
    size_t base = (size_t)bh * NBUK;
    float V1 = 0.f, V2 = 0.f;
    for (int g = 0; g < 8; ++g) {
        float a1[8], a2[8];
#pragma unroll
        for (int r = 0; r < 8; r++) {
            size_t o = ((base + w * 64 + g * 8 + r) * 2) * 64 + lane;
            a1[r] = P[o]; a2[r] = P[o + 64];
        }
#pragma unroll
        for (int r = 0; r < 8; r++) { V1 += a1[r]; a1[r] = V1; V2 += a2[r]; a2[r] = V2; }
#pragma unroll
        for (int r = 0; r < 8; r++) {
            size_t o = ((base + w * 64 + g * 8 + r) * 2) * 64 + lane;
            P[o] = a1[r]; P[o + 64] = a2[r];
        }
    }
    segV[w][0][lane] = V1; segV[w][1][lane] = V2;
    __syncthreads();
    if (w > 0) {
        float O1 = 0.f, O2 = 0.f;
        for (int w2 = 0; w2 < w; w2++) { O1 += segV[w2][0][lane]; O2 += segV[w2][1][lane]; }
        for (int g = 0; g < 8; ++g) {
            float a1[8], a2[8];
#pragma unroll
            for (int r = 0; r < 8; r++) {
                size_t o = ((base + w * 64 + g * 8 + r) * 2) * 64 + lane;
                a1[r] = P[o]; a2[r] = P[o + 64];
            }
#pragma unroll
            for (int r = 0; r < 8; r++) {
                size_t o = ((base + w * 64 + g * 8 + r) * 2) * 64 + lane;
                P[o] = a1[r] + O1; P[o + 64] = a2[r] + O2;
            }
        }
    }
}

// ---------------- apply: rounded-bucket-edge cutoff, pure prefix combine ----------------
// out_i[c] = (c1*(T1[c]-P1[e-1][c]) + c2*P2[e-1][c]) / (c1*(z1tot-z1[e-1]) + c2*z2[e-1])
// e = clamp(round((-d - mn)*scale), 0, 256)  — v-space threshold is -d (exact branch pt).
__global__ __launch_bounds__(256) void k_apply3(const float* __restrict__ P,
                                                const float* __restrict__ zb,
                                                const float* __restrict__ a_dst,
                                                const float* __restrict__ smax_g,
                                                const float2* __restrict__ bparam,
                                                const float* __restrict__ b_gat,
                                                unsigned short* __restrict__ gat) {
    int bh = blockIdx.y, t = threadIdx.x, w = t >> 6, lane = t & 63;
    int b = bh / NH, h = bh % NH;
    float sm = smax_g[bh];
    float2 bp_ = bparam[bh];
    float mn = bp_.x, scale = bp_.y;
    size_t pb = (size_t)bh * NBUK;
    float T1 = P[((pb + NBUK - 1) * 2) * 64 + lane];
    float z1tot = zb[(pb + NBUK - 1) * 2];
    float bias = b_gat[h * 64 + lane];
#pragma unroll
    for (int q = 0; q < 8; q++) {
        int i = blockIdx.x * 32 + w * 8 + q;
        float d = a_dst[(size_t)bh * 1024 + i];
        float dm = d + sm;
        float m = dm > 0.f ? dm : NEG * dm;
        float c1 = __expf(dm - m);
        float c2 = __expf(NEG * dm - m);
        int e = (int)floorf((-d - mn) * scale + 0.5f);
        e = min(max(e, 0), NBUK);
        float P1f = 0.f, P2f = 0.f, z1f = 0.f, z2f = 0.f;
        if (e > 0) {
            size_t o = ((pb + e - 1) * 2) * 64 + lane;
            P1f = P[o]; P2f = P[o + 64];
            z1f = zb[(pb + e - 1) * 2];
            z2f = zb[(pb + e - 1) * 2 + 1];
        }
        float num = c1 * (T1 - P1f) + c2 * P2f;
        float Z = c1 * (z1tot - z1f) + c2 * z2f;
        gat[((size_t)(b * NS + i)) * ND + h * 64 + lane] = f2bf(num / Z + bias);
    }
}

// ---------------- GEMM (m97 structure): C = A1@B1t^T [+ A2@B2t^T] [+bias] ----------------
template <bool DUAL, bool OUT_BF16, bool BIAS>
__global__ __launch_bounds__(256) void k_gemm2(const unsigned short* __restrict__ A1,
                                               const unsigned short* __restrict__ B1,
                                               const unsigned short* __restrict__ A2,
                                               const unsigned short* __restrict__ B2,
                                               const float* __restrict__ bias,
                                               void* __restrict__ Cout,
                                               int MB, int N, int K,
                                               int lda, int ldb1, int ldb2) {
    __shared__ alignas(16) unsigned short sA[128 * 32];
    __shared__ alignas(16) unsigned short sB[128 * 32];
    int nwg = gridDim.x;
    int wg = swz_bid(blockIdx.x, nwg);
    int m0 = (wg % MB) * 128, n0 = (wg / MB) * 128;
    int t = threadIdx.x;
    int wave = t >> 6, lane = t & 63;
    int wm = wave >> 1, wn = wave & 1;
    int lr = lane & 15, kg = (lane >> 4) * 8;
    int srow = t >> 2, scol = (t & 3) * 8;
    unsigned short* lA1 = &sA[t * 8];
    unsigned short* lA2 = &sA[2048 + t * 8];
    unsigned short* lB1 = &sB[t * 8];
    unsigned short* lB2 = &sB[2048 + t * 8];
    f32x4 acc[4][4] = {};
#pragma unroll 1
    for (int phase = 0; phase < (DUAL ? 2 : 1); phase++) {
        const unsigned short* A = (DUAL && phase) ? A2 : A1;
        const unsigned short* Bt = (DUAL && phase) ? B2 : B1;
        int ldb = (DUAL && phase) ? ldb2 : ldb1;
        const unsigned short* gA1 = A + (size_t)(m0 + srow) * lda + scol;
        const unsigned short* gA2 = gA1 + (size_t)64 * lda;
        const unsigned short* gB1 = Bt + (size_t)(n0 + srow) * ldb + scol;
        const unsigned short* gB2 = gB1 + (size_t)64 * ldb;
        for (int k0 = 0; k0 < K; k0 += 32) {
            __syncthreads();
            gload16(gA1 + k0, lA1);
            gload16(gA2 + k0, lA2);
            gload16(gB1 + k0, lB1);
            gload16(gB2 + k0, lB2);
            __syncthreads();
            bf16x8 af[4], bfr[4];
#pragma unroll
            for (int m = 0; m < 4; m++)
                af[m] = *reinterpret_cast<bf16x8*>(&sA[(wm * 64 + m * 16 + lr) * 32 + kg]);
#pragma unroll
            for (int n = 0; n < 4; n++)
                bfr[n] = *reinterpret_cast<bf16x8*>(&sB[(wn * 64 + n * 16 + lr) * 32 + kg]);
#pragma unroll
            for (int m = 0; m < 4; m++)
#pragma unroll
                for (int n = 0; n < 4; n++)
                    acc[m][n] = __builtin_amdgcn_mfma_f32_16x16x32_bf16(af[m], bfr[n], acc[m][n], 0, 0, 0);
        }
    }
    int rg = (lane >> 4) * 4;
#pragma unroll
    for (int m = 0; m < 4; m++) {
#pragma unroll
        for (int n = 0; n < 4; n++) {
            int col = n0 + wn * 64 + n * 16 + lr;
            float bv = BIAS ? bias[col] : 0.0f;
#pragma unroll
            for (int r = 0; r < 4; r++) {
                int row = m0 + wm * 64 + m * 16 + rg + r;
                float v = acc[m][n][r] + bv;
                if (OUT_BF16) {
                    ((unsigned short*)Cout)[(size_t)row * N + col] = f2bf(v);
                } else {
                    ((float*)Cout)[(size_t)row * N + col] = v;
                }
            }
        }
    }
}

extern "C" void kernel_launch(void* const* d_in, const int* in_sizes, int n_in,
                              void* d_out, int out_size, void* d_ws, size_t ws_size,
                              hipStream_t stream) {
    const float* hs  = (const float*)d_in[0];
    const float* to  = (const float*)d_in[1];
    const float* Wg  = (const float*)d_in[2];
    const float* asv = (const float*)d_in[3];
    const float* adv = (const float*)d_in[4];
    const float* bg  = (const float*)d_in[5];
    const float* Wp  = (const float*)d_in[6];
    const float* bp  = (const float*)d_in[7];
    const float* Wf  = (const float*)d_in[8];
    const float* bfu = (const float*)d_in[9];
    float* out = (float*)d_out;

    char* ws = (char*)d_ws;
    size_t off = 0;
    auto alloc = [&](size_t bytes) -> void* {
        void* p = ws + off;
        off = (off + bytes + 255) & ~(size_t)255;
        return p;
    };
    const size_t NBSD = (size_t)NB * NS * ND;
    const int NBH = NB * NH;
    unsigned short* h_bf   = (unsigned short*)alloc(NBSD * 2);  // later reused as gat_bf
    unsigned short* x_bf   = (unsigned short*)alloc(NBSD * 2);
    unsigned short* t_bf   = (unsigned short*)alloc(NBSD * 2);
    unsigned short* WgT    = (unsigned short*)alloc((size_t)ND * ND * 2);
    unsigned short* Wp_bf  = (unsigned short*)alloc((size_t)ND * ND * 2);
    unsigned short* WfT    = (unsigned short*)alloc((size_t)2 * ND * ND * 2);
    unsigned short* WcombT = (unsigned short*)alloc((size_t)ND * ND * 2);
    float*  bias_tot = (float*)alloc((size_t)ND * 4);
    float*  a_src = (float*)alloc((size_t)NBH * NS * 4);
    float*  a_dst = (float*)alloc((size_t)NBH * NS * 4);
    float4* pack  = (float4*)alloc((size_t)NBH * NS * 16);
    int*    bstart = (int*)alloc((size_t)NBH * 257 * 4);
    float*  P     = (float*)alloc((size_t)NBH * NBUK * 2 * 64 * 4);
    float*  zb    = (float*)alloc((size_t)NBH * NBUK * 2 * 4);
    float*  smaxb = (float*)alloc((size_t)NBH * 4);
    float2* bparam = (float2*)alloc((size_t)NBH * 8);

    int n = (int)NBSD;
    k_conv2<<<2 * (n / 4) / 256, 256, 0, stream>>>(hs, to, h_bf, t_bf, n / 4);
    k_f32_to_bf16<<<(ND * ND) / 4 / 256, 256, 0, stream>>>(Wp, Wp_bf, ND * ND);
    k_transpose_conv<<<dim3(ND / 32, ND / 32), 256, 0, stream>>>(Wg, WgT, ND, ND);
    k_transpose_conv<<<dim3(ND / 32, 2 * ND / 32), 256, 0, stream>>>(Wf, WfT, 2 * ND, ND);

    // WcombT = (Wp @ Wf_bot)^T : WcombT[n][k] = sum_r WfT[n][768+r] * Wp_bf[k][r]
    k_gemm2<false, true, false><<<(ND / 128) * (ND / 128), 256, 0, stream>>>(
        WfT + ND, Wp_bf, nullptr, nullptr, nullptr, WcombT, ND / 128, ND, ND, 2 * ND, ND, 0);
    k_bias_tot<<<ND * 8 / 256, 256, 0, stream>>>(Wf, bp, bfu, bias_tot);

    // GEMM1: x = hs @ W_gat  -> bf16
    k_gemm2<false, true, false><<<(NB * NS / 128) * (ND / 128), 256, 0, stream>>>(
        h_bf, WgT, nullptr, nullptr, nullptr, x_bf, NB * NS / 128, ND, ND, ND, ND, 0);

    k_attn_vec<<<NB * NS / 16, 192, 0, stream>>>(x_bf, asv, adv, a_src, a_dst);
    k_bucket<<<NBH, 256, 0, stream>>>(a_src, pack, bstart, smaxb, bparam, zb);
    k_bsum<<<dim3(NBUK / 8, NBH), 256, 0, stream>>>(x_bf, pack, bstart, P);
    k_bpref<<<NBH, 256, 0, stream>>>(P);

    unsigned short* gat_bf = h_bf;
    k_apply3<<<dim3(NS / 32, NBH), 256, 0, stream>>>(P, zb, a_dst, smaxb, bparam, bg, gat_bf);

    // out = t @ Wf_top + gat @ Wcomb + bias_tot
    k_gemm2<true, false, true><<<(NB * NS / 128) * (ND / 128), 256, 0, stream>>>(
        t_bf, WfT, gat_bf, WcombT, bias_tot, out, NB * NS / 128, ND, ND, ND, 2 * ND, ND);
}

// Round 6
// 171.617 us; speedup vs baseline: 2.1134x; 1.0750x over previous
//
#include <hip/hip_runtime.h>
#include <hip/hip_bf16.h>

#define NB 8
#define NS 1024
#define ND 768
#define NH 12
#define NC 64
#define NEG 0.2f
#define NBUK 128

typedef __attribute__((ext_vector_type(8))) short bf16x8;
typedef __attribute__((ext_vector_type(4))) float f32x4;

static __device__ __forceinline__ float bf2f(unsigned short u) {
    union { float f; unsigned int i; } v; v.i = ((unsigned int)u) << 16; return v.f;
}
static __device__ __forceinline__ unsigned short f2bf(float f) {
    union { float f; unsigned int i; } v; v.f = f;
    unsigned int r = v.i + 0x7FFFu + ((v.i >> 16) & 1u);
    return (unsigned short)(r >> 16);
}

static __device__ __forceinline__ void gload16(const unsigned short* g, unsigned short* l) {
    __builtin_amdgcn_global_load_lds((const __attribute__((address_space(1))) void*)g,
                                     (__attribute__((address_space(3))) void*)l, 16, 0, 0);
}

// bijective XCD-chunk swizzle (m204)
static __device__ __forceinline__ int swz_bid(int orig, int nwg) {
    int q = nwg >> 3, r = nwg & 7;
    int xcd = orig & 7, idx = orig >> 3;
    return (xcd < r ? xcd * (q + 1) : r * (q + 1) + (xcd - r) * q) + idx;
}

// ---------------- fp32 -> bf16 convert: hs, to, Wp in one launch ----------------
__global__ void k_convall(const float* __restrict__ a, const float* __restrict__ b,
                          const float* __restrict__ c,
                          unsigned short* __restrict__ oa, unsigned short* __restrict__ ob,
                          unsigned short* __restrict__ oc, int n1, int n2) {
    int gid = blockIdx.x * 256 + threadIdx.x;
    const float* s; unsigned short* d; int i;
    if (gid < n1) { s = a; d = oa; i = gid; }
    else if (gid < 2 * n1) { s = b; d = ob; i = gid - n1; }
    else { s = c; d = oc; i = gid - 2 * n1; if (i >= n2) return; }
    i *= 4;
    float4 v = *reinterpret_cast<const float4*>(s + i);
    ushort4 o;
    o.x = f2bf(v.x); o.y = f2bf(v.y); o.z = f2bf(v.z); o.w = f2bf(v.w);
    *reinterpret_cast<ushort4*>(d + i) = o;
}

// ---------------- fp32 [K,N] -> bf16 [N,K] transpose-convert (Wg + Wf merged) ----------------
__global__ void k_tconv2(const float* __restrict__ Wg, const float* __restrict__ Wf,
                         unsigned short* __restrict__ WgT, unsigned short* __restrict__ WfT) {
    __shared__ float tile[32][33];
    int by = blockIdx.y;
    const float* src; unsigned short* dst; int K, k0;
    if (by < ND / 32) { src = Wg; dst = WgT; K = ND; k0 = by * 32; }
    else { src = Wf; dst = WfT; K = 2 * ND; k0 = (by - ND / 32) * 32; }
    int n0 = blockIdx.x * 32;
    int t = threadIdx.x;           // 256 threads
    int r = t >> 3, c4 = (t & 7) * 4;
    float4 v = *reinterpret_cast<const float4*>(src + (size_t)(k0 + r) * ND + n0 + c4);
    tile[r][c4] = v.x; tile[r][c4 + 1] = v.y; tile[r][c4 + 2] = v.z; tile[r][c4 + 3] = v.w;
    __syncthreads();
    ushort4 o;
    o.x = f2bf(tile[c4][r]); o.y = f2bf(tile[c4 + 1][r]);
    o.z = f2bf(tile[c4 + 2][r]); o.w = f2bf(tile[c4 + 3][r]);
    *reinterpret_cast<ushort4*>(dst + (size_t)(n0 + r) * K + k0 + c4) = o;
}

// ---------------- combined bias: bias_tot[c] = b_fus[c] + sum_k bp[k]*Wf[768+k][c] ----------------
__global__ void k_bias_tot(const float* __restrict__ Wf, const float* __restrict__ bp,
                           const float* __restrict__ bfu, float* __restrict__ bias_tot) {
    int gid = blockIdx.x * 256 + threadIdx.x;   // 24 blocks: (c, slice)
    int c = gid >> 3, sl = gid & 7;
    float acc = 0.f;
    int k0 = sl * 96;
#pragma unroll 8
    for (int k = k0; k < k0 + 96; k++) acc += bp[k] * Wf[(size_t)(ND + k) * ND + c];
    acc += __shfl_down(acc, 1, 64);
    acc += __shfl_down(acc, 2, 64);
    acc += __shfl_down(acc, 4, 64);
    if (sl == 0) bias_tot[c] = acc + bfu[c];
}

// ---------------- a_src / a_dst: thread-per-(row,head) ----------------
__global__ __launch_bounds__(192) void k_attn_vec(const unsigned short* __restrict__ x,
                                                  const float* __restrict__ att_src,
                                                  const float* __restrict__ att_dst,
                                                  float* __restrict__ a_src,
                                                  float* __restrict__ a_dst) {
    __shared__ float s_src[ND], s_dst[ND];
    int t = threadIdx.x;
    for (int i = t; i < ND; i += 192) { s_src[i] = att_src[i]; s_dst[i] = att_dst[i]; }
    __syncthreads();
    int rl = t / 12, h = t - rl * 12;
    int bs = blockIdx.x * 16 + rl;
    const unsigned short* xr = x + (size_t)bs * ND + h * 64;
    float ps = 0.f, pd = 0.f;
#pragma unroll
    for (int j0 = 0; j0 < 64; j0 += 8) {
        bf16x8 v = *reinterpret_cast<const bf16x8*>(xr + j0);
#pragma unroll
        for (int j = 0; j < 8; j++) {
            float xv = bf2f((unsigned short)v[j]);
            ps = fmaf(xv, s_src[h * 64 + j0 + j], ps);
            pd = fmaf(xv, s_dst[h * 64 + j0 + j], pd);
        }
    }
    int b = bs >> 10, s = bs & 1023;
    a_src[((size_t)b * NH + h) * NS + s] = ps;
    a_dst[((size_t)b * NH + h) * NS + s] = pd;
}

// ---------------- counting sort into NBUK buckets + fused z-prefix ----------------
__global__ __launch_bounds__(256) void k_bucket(const float* __restrict__ a_src,
                                                float4* __restrict__ pack,
                                                int* __restrict__ bstart,
                                                float* __restrict__ smax_g,
                                                float2* __restrict__ bparam,
                                                float* __restrict__ zb) {
    int bh = blockIdx.x, t = threadIdx.x;
    __shared__ float v[1024];
    __shared__ int bi[1024];
    __shared__ float red[256];
    __shared__ int cnt[NBUK], pre[NBUK];
    __shared__ float zs1[NBUK], zs2[NBUK];
    for (int i = t; i < 1024; i += 256) v[i] = a_src[(size_t)bh * 1024 + i];
    if (t < NBUK) { cnt[t] = 0; zs1[t] = 0.f; zs2[t] = 0.f; }
    __syncthreads();
    float lm = -1e30f, ln = 1e30f;
    for (int i = t; i < 1024; i += 256) { lm = fmaxf(lm, v[i]); ln = fminf(ln, v[i]); }
    red[t] = lm; __syncthreads();
    for (int s = 128; s > 0; s >>= 1) { if (t < s) red[t] = fmaxf(red[t], red[t + s]); __syncthreads(); }
    float mx = red[0]; __syncthreads();
    red[t] = ln; __syncthreads();
    for (int s = 128; s > 0; s >>= 1) { if (t < s) red[t] = fminf(red[t], red[t + s]); __syncthreads(); }
    float mn = red[0]; __syncthreads();
    float scale = (float)NBUK / fmaxf(mx - mn, 1e-20f);
    for (int i = t; i < 1024; i += 256) {
        int bk = (int)((v[i] - mn) * scale);
        bk = min(max(bk, 0), NBUK - 1);
        bi[i] = bk;
        atomicAdd(&cnt[bk], 1);
    }
    __syncthreads();
    if (t < NBUK) pre[t] = cnt[t];
    __syncthreads();
    for (int off = 1; off < NBUK; off <<= 1) {
        int x = (t >= off && t < NBUK) ? pre[t - off] : 0;
        __syncthreads();
        if (t < NBUK) pre[t] += x;
        __syncthreads();
    }
    if (t < NBUK) {
        int start = pre[t] - cnt[t];
        bstart[bh * (NBUK + 1) + t] = start;
        cnt[t] = start;   // reuse as running offsets
    }
    if (t == 0) {
        bstart[bh * (NBUK + 1) + NBUK] = 1024;
        smax_g[bh] = mx;
        bparam[bh] = make_float2(mn, scale);
    }
    __syncthreads();
    for (int i = t; i < 1024; i += 256) {
        int pos = atomicAdd(&cnt[bi[i]], 1);
        float u = v[i] - mx;
        float4 p;
        p.x = u; p.y = __expf(u); p.z = __expf(0.2f * u); p.w = __int_as_float(i);
        pack[(size_t)bh * 1024 + pos] = p;
        atomicAdd(&zs1[bi[i]], p.y);
        atomicAdd(&zs2[bi[i]], p.z);
    }
    __syncthreads();
    for (int off = 1; off < NBUK; off <<= 1) {
        float x1 = (t >= off && t < NBUK) ? zs1[t - off] : 0.f;
        float x2 = (t >= off && t < NBUK) ? zs2[t - off] : 0.f;
        __syncthreads();
        if (t < NBUK) { zs1[t] += x1; zs2[t] += x2; }
        __syncthreads();
    }
    if (t < NBUK) {
        zb[(size_t)(bh * NBUK + t) * 2] = zs1[t];
        zb[(size_t)(bh * NBUK + t) * 2 + 1] = zs2[t];
    }
}

// ---------------- per-bucket vector sums (64 ch) ----------------
__global__ __launch_bounds__(256) void k_bsum(const unsigned short* __restrict__ x_bf,
                                              const float4* __restrict__ pack,
                                              const int* __restrict__ bstart,
                                              float* __restrict__ P) {
    int grp = blockIdx.x, bh = blockIdx.y;
    int t = threadIdx.x, w = t >> 6, lane = t & 63;
    int b = bh / NH, h = bh % NH;
    const float4* pk = pack + (size_t)bh * 1024;
    const unsigned short* xb = x_bf + (size_t)b * NS * ND + h * 64 + lane;
#pragma unroll
    for (int r = 0; r < 2; r++) {
        int bk = grp * 8 + w * 2 + r;
        int ks = bstart[bh * (NBUK + 1) + bk], ke = bstart[bh * (NBUK + 1) + bk + 1];
        float V1 = 0.f, V2 = 0.f;
        for (int k = ks; k < ke; k++) {
            float4 p = pk[k];
            int j = __float_as_int(p.w);
            float xv = bf2f(xb[(size_t)j * ND]);
            V1 += p.y * xv; V2 += p.z * xv;
        }
        size_t o = ((size_t)(bh * NBUK + bk) * 2) * 64 + lane;
        P[o] = V1; P[o + 64] = V2;
    }
}

// ---------------- inclusive prefix over buckets for vectors P ----------------
__global__ __launch_bounds__(256) void k_bpref(float* __restrict__ P) {
    int bh = blockIdx.x, t = threadIdx.x, w = t >> 6, lane = t & 63;
    __shared__ float segV[4][2][64];
    size_t base = (size_t)bh * NBUK;
    float V1 = 0.f, V2 = 0.f;
    for (int g = 0; g < 4; ++g) {
        float a1[8], a2[8];
#pragma unroll
        for (int r = 0; r < 8; r++) {
            size_t o = ((base + w * 32 + g * 8 + r) * 2) * 64 + lane;
            a1[r] = P[o]; a2[r] = P[o + 64];
        }
#pragma unroll
        for (int r = 0; r < 8; r++) { V1 += a1[r]; a1[r] = V1; V2 += a2[r]; a2[r] = V2; }
#pragma unroll
        for (int r = 0; r < 8; r++) {
            size_t o = ((base + w * 32 + g * 8 + r) * 2) * 64 + lane;
            P[o] = a1[r]; P[o + 64] = a2[r];
        }
    }
    segV[w][0][lane] = V1; segV[w][1][lane] = V2;
    __syncthreads();
    if (w > 0) {
        float O1 = 0.f, O2 = 0.f;
        for (int w2 = 0; w2 < w; w2++) { O1 += segV[w2][0][lane]; O2 += segV[w2][1][lane]; }
        for (int g = 0; g < 4; ++g) {
            float a1[8], a2[8];
#pragma unroll
            for (int r = 0; r < 8; r++) {
                size_t o = ((base + w * 32 + g * 8 + r) * 2) * 64 + lane;
                a1[r] = P[o]; a2[r] = P[o + 64];
            }
#pragma unroll
            for (int r = 0; r < 8; r++) {
                size_t o = ((base + w * 32 + g * 8 + r) * 2) * 64 + lane;
                P[o] = a1[r] + O1; P[o + 64] = a2[r] + O2;
            }
        }
    }
}

// ---------------- apply: rounded-bucket-edge cutoff, pure prefix combine ----------------
__global__ __launch_bounds__(256) void k_apply3(const float* __restrict__ P,
                                                const float* __restrict__ zb,
                                                const float* __restrict__ a_dst,
                                                const float* __restrict__ smax_g,
                                                const float2* __restrict__ bparam,
                                                const float* __restrict__ b_gat,
                                                unsigned short* __restrict__ gat) {
    int bh = blockIdx.y, t = threadIdx.x, w = t >> 6, lane = t & 63;
    int b = bh / NH, h = bh % NH;
    float sm = smax_g[bh];
    float2 bp_ = bparam[bh];
    float mn = bp_.x, scale = bp_.y;
    size_t pb = (size_t)bh * NBUK;
    float T1 = P[((pb + NBUK - 1) * 2) * 64 + lane];
    float z1tot = zb[(pb + NBUK - 1) * 2];
    float bias = b_gat[h * 64 + lane];
#pragma unroll
    for (int q = 0; q < 8; q++) {
        int i = blockIdx.x * 32 + w * 8 + q;
        float d = a_dst[(size_t)bh * 1024 + i];
        float dm = d + sm;
        float m = dm > 0.f ? dm : NEG * dm;
        float c1 = __expf(dm - m);
        float c2 = __expf(NEG * dm - m);
        int e = (int)floorf((-d - mn) * scale + 0.5f);
        e = min(max(e, 0), NBUK);
        float P1f = 0.f, P2f = 0.f, z1f = 0.f, z2f = 0.f;
        if (e > 0) {
            size_t o = ((pb + e - 1) * 2) * 64 + lane;
            P1f = P[o]; P2f = P[o + 64];
            z1f = zb[(pb + e - 1) * 2];
            z2f = zb[(pb + e - 1) * 2 + 1];
        }
        float num = c1 * (T1 - P1f) + c2 * P2f;
        float Z = c1 * (z1tot - z1f) + c2 * z2f;
        gat[((size_t)(b * NS + i)) * ND + h * 64 + lane] = f2bf(num / Z + bias);
    }
}

// ---------------- GEMM: 64x128 tile, BK=32, 4 waves (each 64x32), gload_lds staging ----------------
// C[M,N] = A1@B1t^T [+ A2@B2t^T] [+bias]; grid = MB * (N/128), m-fastest + XCD swizzle.
template <bool DUAL, bool OUT_BF16, bool BIAS>
__global__ __launch_bounds__(256) void k_gemm3(const unsigned short* __restrict__ A1,
                                               const unsigned short* __restrict__ B1,
                                               const unsigned short* __restrict__ A2,
                                               const unsigned short* __restrict__ B2,
                                               const float* __restrict__ bias,
                                               void* __restrict__ Cout,
                                               int MB, int N, int K,
                                               int lda, int ldb1, int ldb2) {
    __shared__ alignas(16) unsigned short sA[64 * 32];
    __shared__ alignas(16) unsigned short sB[128 * 32];
    int wg = swz_bid(blockIdx.x, gridDim.x);
    int m0 = (wg % MB) * 64, n0 = (wg / MB) * 128;
    int t = threadIdx.x;
    int wave = t >> 6, lane = t & 63;
    int lr = lane & 15, kg = (lane >> 4) * 8;
    int srow = t >> 2, scol = (t & 3) * 8;
    unsigned short* lA = &sA[t * 8];
    unsigned short* lB1 = &sB[t * 8];
    unsigned short* lB2 = &sB[2048 + t * 8];
    f32x4 acc[4][2] = {};
#pragma unroll 1
    for (int phase = 0; phase < (DUAL ? 2 : 1); phase++) {
        const unsigned short* A = (DUAL && phase) ? A2 : A1;
        const unsigned short* Bt = (DUAL && phase) ? B2 : B1;
        int ldb = (DUAL && phase) ? ldb2 : ldb1;
        const unsigned short* gA = A + (size_t)(m0 + srow) * lda + scol;
        const unsigned short* gB1 = Bt + (size_t)(n0 + srow) * ldb + scol;
        const unsigned short* gB2 = gB1 + (size_t)64 * ldb;
        for (int k0 = 0; k0 < K; k0 += 32) {
            __syncthreads();
            gload16(gA + k0, lA);
            gload16(gB1 + k0, lB1);
            gload16(gB2 + k0, lB2);
            __syncthreads();
            bf16x8 af[4], bfr[2];
#pragma unroll
            for (int m = 0; m < 4; m++)
                af[m] = *reinterpret_cast<bf16x8*>(&sA[(m * 16 + lr) * 32 + kg]);
#pragma unroll
            for (int n = 0; n < 2; n++)
                bfr[n] = *reinterpret_cast<bf16x8*>(&sB[(wave * 32 + n * 16 + lr) * 32 + kg]);
#pragma unroll
            for (int m = 0; m < 4; m++)
#pragma unroll
                for (int n = 0; n < 2; n++)
                    acc[m][n] = __builtin_amdgcn_mfma_f32_16x16x32_bf16(af[m], bfr[n], acc[m][n], 0, 0, 0);
        }
    }
    int rg = (lane >> 4) * 4;
#pragma unroll
    for (int m = 0; m < 4; m++) {
#pragma unroll
        for (int n = 0; n < 2; n++) {
            int col = n0 + wave * 32 + n * 16 + lr;
            float bv = BIAS ? bias[col] : 0.0f;
#pragma unroll
            for (int r = 0; r < 4; r++) {
                int row = m0 + m * 16 + rg + r;
                float v = acc[m][n][r] + bv;
                if (OUT_BF16) {
                    ((unsigned short*)Cout)[(size_t)row * N + col] = f2bf(v);
                } else {
                    ((float*)Cout)[(size_t)row * N + col] = v;
                }
            }
        }
    }
}

extern "C" void kernel_launch(void* const* d_in, const int* in_sizes, int n_in,
                              void* d_out, int out_size, void* d_ws, size_t ws_size,
                              hipStream_t stream) {
    const float* hs  = (const float*)d_in[0];
    const float* to  = (const float*)d_in[1];
    const float* Wg  = (const float*)d_in[2];
    const float* asv = (const float*)d_in[3];
    const float* adv = (const float*)d_in[4];
    const float* bg  = (const float*)d_in[5];
    const float* Wp  = (const float*)d_in[6];
    const float* bp  = (const float*)d_in[7];
    const float* Wf  = (const float*)d_in[8];
    const float* bfu = (const float*)d_in[9];
    float* out = (float*)d_out;

    char* ws = (char*)d_ws;
    size_t off = 0;
    auto alloc = [&](size_t bytes) -> void* {
        void* p = ws + off;
        off = (off + bytes + 255) & ~(size_t)255;
        return p;
    };
    const size_t NBSD = (size_t)NB * NS * ND;
    const int NBH = NB * NH;
    unsigned short* h_bf   = (unsigned short*)alloc(NBSD * 2);  // later reused as gat_bf
    unsigned short* x_bf   = (unsigned short*)alloc(NBSD * 2);
    unsigned short* t_bf   = (unsigned short*)alloc(NBSD * 2);
    unsigned short* WgT    = (unsigned short*)alloc((size_t)ND * ND * 2);
    unsigned short* Wp_bf  = (unsigned short*)alloc((size_t)ND * ND * 2);
    unsigned short* WfT    = (unsigned short*)alloc((size_t)2 * ND * ND * 2);
    unsigned short* WcombT = (unsigned short*)alloc((size_t)ND * ND * 2);
    float*  bias_tot = (float*)alloc((size_t)ND * 4);
    float*  a_src = (float*)alloc((size_t)NBH * NS * 4);
    float*  a_dst = (float*)alloc((size_t)NBH * NS * 4);
    float4* pack  = (float4*)alloc((size_t)NBH * NS * 16);
    int*    bstart = (int*)alloc((size_t)NBH * (NBUK + 1) * 4);
    float*  P     = (float*)alloc((size_t)NBH * NBUK * 2 * 64 * 4);
    float*  zb    = (float*)alloc((size_t)NBH * NBUK * 2 * 4);
    float*  smaxb = (float*)alloc((size_t)NBH * 4);
    float2* bparam = (float2*)alloc((size_t)NBH * 8);

    int n1 = (int)NBSD / 4, n2 = ND * ND / 4;
    k_convall<<<(2 * n1 + n2 + 255) / 256, 256, 0, stream>>>(hs, to, Wp, h_bf, t_bf, Wp_bf, n1, n2);
    k_tconv2<<<dim3(ND / 32, 3 * ND / 32), 256, 0, stream>>>(Wg, Wf, WgT, WfT);

    // WcombT = (Wp @ Wf_bot)^T : WcombT[n][k] = sum_r WfT[n][768+r] * Wp_bf[k][r]
    k_gemm3<false, true, false><<<(ND / 64) * (ND / 128), 256, 0, stream>>>(
        WfT + ND, Wp_bf, nullptr, nullptr, nullptr, WcombT, ND / 64, ND, ND, 2 * ND, ND, 0);
    k_bias_tot<<<ND * 8 / 256, 256, 0, stream>>>(Wf, bp, bfu, bias_tot);

    // GEMM1: x = hs @ W_gat  -> bf16
    k_gemm3<false, true, false><<<(NB * NS / 64) * (ND / 128), 256, 0, stream>>>(
        h_bf, WgT, nullptr, nullptr, nullptr, x_bf, NB * NS / 64, ND, ND, ND, ND, 0);

    k_attn_vec<<<NB * NS / 16, 192, 0, stream>>>(x_bf, asv, adv, a_src, a_dst);
    k_bucket<<<NBH, 256, 0, stream>>>(a_src, pack, bstart, smaxb, bparam, zb);
    k_bsum<<<dim3(NBUK / 8, NBH), 256, 0, stream>>>(x_bf, pack, bstart, P);
    k_bpref<<<NBH, 256, 0, stream>>>(P);

    unsigned short* gat_bf = h_bf;
    k_apply3<<<dim3(NS / 32, NBH), 256, 0, stream>>>(P, zb, a_dst, smaxb, bparam, bg, gat_bf);

    // out = t @ Wf_top + gat @ Wcomb + bias_tot
    k_gemm3<true, false, true><<<(NB * NS / 64) * (ND / 128), 256, 0, stream>>>(
        t_bf, WfT, gat_bf, WcombT, bias_tot, out, NB * NS / 64, ND, ND, ND, 2 * ND, ND);
}